// Round 1
// baseline (843.517 us; speedup 1.0000x reference)
//
#include <hip/hip_runtime.h>
#include <hip/hip_bf16.h>

// Problem constants: B=8, N=1024, C=768, H=12, D=64, M=128
#define PB 8
#define PN 1024
#define PC 768
#define PH 12
#define PD 64
#define PM 128
#define SQ 0.35355339059327373f      // (D^-0.5)^0.5
#define MSCALE 0.08838834764831843f  // M^-0.5

// ---------------- NT GEMM: C[i,j] = sum_k A[i,k]*B[j,k] (+bias[j]) ----------------
// A: [Mdim,Kdim] row-major, B: [Ndim,Kdim] row-major. 64x64 tile, 256 thr, 4x4 micro.
__global__ __launch_bounds__(256) void gemm_nt_bias(
        const float* __restrict__ A, const float* __restrict__ Bm, float* __restrict__ Cm,
        int Mdim, int Ndim, int Kdim, const float* __restrict__ bias)
{
    __shared__ float As[16][68];
    __shared__ float Bs[16][68];
    const int t  = threadIdx.x;
    const int tx = t & 15, ty = t >> 4;
    const int bi = blockIdx.y * 64, bj = blockIdx.x * 64;
    const int lk = t & 15;   // k within tile
    const int lr = t >> 4;   // row 0..15 (step 16)
    float acc[4][4] = {{0.f}};
    const float* Ap = A  + (size_t)(bi + lr) * Kdim + lk;
    const float* Bp = Bm + (size_t)(bj + lr) * Kdim + lk;
    for (int k0 = 0; k0 < Kdim; k0 += 16) {
        #pragma unroll
        for (int r = 0; r < 64; r += 16) {
            As[lk][lr + r] = Ap[(size_t)r * Kdim + k0];
            Bs[lk][lr + r] = Bp[(size_t)r * Kdim + k0];
        }
        __syncthreads();
        #pragma unroll
        for (int kk = 0; kk < 16; ++kk) {
            float4 av = *(const float4*)&As[kk][ty * 4];
            float4 bv = *(const float4*)&Bs[kk][tx * 4];
            acc[0][0] += av.x * bv.x; acc[0][1] += av.x * bv.y;
            acc[0][2] += av.x * bv.z; acc[0][3] += av.x * bv.w;
            acc[1][0] += av.y * bv.x; acc[1][1] += av.y * bv.y;
            acc[1][2] += av.y * bv.z; acc[1][3] += av.y * bv.w;
            acc[2][0] += av.z * bv.x; acc[2][1] += av.z * bv.y;
            acc[2][2] += av.z * bv.z; acc[2][3] += av.z * bv.w;
            acc[3][0] += av.w * bv.x; acc[3][1] += av.w * bv.y;
            acc[3][2] += av.w * bv.z; acc[3][3] += av.w * bv.w;
        }
        __syncthreads();
    }
    #pragma unroll
    for (int a = 0; a < 4; ++a) {
        int row = bi + ty * 4 + a;
        #pragma unroll
        for (int b = 0; b < 4; ++b) {
            int col = bj + tx * 4 + b;
            float v = acc[a][b];
            if (bias) v += bias[col];
            Cm[(size_t)row * Ndim + col] = v;
        }
    }
}

// ---------------- Feature map: qf/kf = exp(z@R[h] - 0.5|z|^2) * M^-0.5 ----------------
// grid.x = B*H*(N/16), grid.y = 2 (0=q, 1=k); 128 threads (one per m).
__global__ __launch_bounds__(128) void feat_map(
        const float* __restrict__ qkv, const float* __restrict__ rm,
        float* __restrict__ qf, float* __restrict__ kf)
{
    __shared__ float R[64][128];
    __shared__ float zs[16][64];
    const int t = threadIdx.x;
    const int which = blockIdx.y;
    int bx = blockIdx.x;
    const int chunk = bx & 63; bx >>= 6;     // N/16 = 64 chunks
    const int h = bx % PH, b = bx / PH;
    const int n0 = chunk * 16;
    float* outp = (which == 0) ? qf : kf;

    const float* rh = rm + (size_t)h * 64 * 128;
    #pragma unroll
    for (int i = 0; i < 64; ++i) R[i][t] = rh[i * 128 + t];

    const float* qbase = qkv + (size_t)(b * PN + n0) * (3 * PC) + which * PC + h * PD;
    #pragma unroll
    for (int i = 0; i < 8; ++i) {
        int idx = i * 128 + t;
        int row = idx >> 6, d = idx & 63;
        zs[row][d] = qbase[(size_t)row * (3 * PC) + d] * SQ;
    }
    __syncthreads();

    float* op = outp + ((size_t)((b * PH + h) * PN + n0)) * PM + t;
    for (int r = 0; r < 16; ++r) {
        float logit = 0.f, sq2 = 0.f;
        #pragma unroll
        for (int d = 0; d < 64; ++d) {
            float z = zs[r][d];
            logit += z * R[d][t];
            sq2   += z * z;
        }
        op[(size_t)r * PM] = __expf(logit - 0.5f * sq2) * MSCALE;
    }
}

// ---------------- KV = kf^T @ v  [B,H,M,D], s = column sums of kf [B,H,M] ----------------
// grid (B*H, D/8); 256 threads. Each thread: one m (t&127), 4 d's.
__global__ __launch_bounds__(256) void kv_s_kernel(
        const float* __restrict__ qkv, const float* __restrict__ kf,
        float* __restrict__ kv, float* __restrict__ s)
{
    __shared__ float kfs[64][128];
    __shared__ float vs[64][8];
    const int t = threadIdx.x;
    const int bh = blockIdx.x;
    const int b = bh / PH, h = bh % PH;
    const int dc0 = blockIdx.y * 8;
    const int m = t & 127;
    const int half = t >> 7;
    float acc[4] = {0.f, 0.f, 0.f, 0.f};
    float sacc = 0.f;
    const float* kfb = kf + (size_t)bh * PN * PM;
    const float* vb  = qkv + (size_t)b * PN * (3 * PC) + 2 * PC + h * PD + dc0;
    for (int n0 = 0; n0 < PN; n0 += 64) {
        #pragma unroll
        for (int i = 0; i < 32; ++i) {
            int idx = i * 256 + t;
            kfs[idx >> 7][idx & 127] = kfb[(size_t)(n0 + (idx >> 7)) * PM + (idx & 127)];
        }
        #pragma unroll
        for (int i = 0; i < 2; ++i) {
            int idx = i * 256 + t;
            int row = idx >> 3, dd = idx & 7;
            vs[row][dd] = vb[(size_t)(n0 + row) * (3 * PC) + dd];
        }
        __syncthreads();
        #pragma unroll 8
        for (int nn = 0; nn < 64; ++nn) {
            float kq = kfs[nn][m];
            sacc += kq;
            #pragma unroll
            for (int j = 0; j < 4; ++j)
                acc[j] += kq * vs[nn][half * 4 + j];
        }
        __syncthreads();
    }
    float* kvp = kv + ((size_t)bh * PM + m) * PD + dc0 + half * 4;
    #pragma unroll
    for (int j = 0; j < 4; ++j) kvp[j] = acc[j];
    if (blockIdx.y == 0 && half == 0) s[bh * PM + m] = sacc;
}

// ---------------- denom[b,h,n] = max(qf . s, EPS) ----------------
// grid B*H*16; 256 threads = 4 waves, each wave one row per iter.
__global__ __launch_bounds__(256) void denom_kernel(
        const float* __restrict__ qf, const float* __restrict__ s, float* __restrict__ denom)
{
    __shared__ float ss[128];
    const int t = threadIdx.x;
    const int bh = blockIdx.x >> 4;
    const int n0 = (blockIdx.x & 15) * 64;
    if (t < 128) ss[t] = s[bh * PM + t];
    __syncthreads();
    const int wave = t >> 6, lane = t & 63;
    const float* qb = qf + ((size_t)bh * PN + n0) * PM;
    for (int it = 0; it < 16; ++it) {
        int r = it * 4 + wave;
        float p = qb[(size_t)r * PM + lane] * ss[lane]
                + qb[(size_t)r * PM + 64 + lane] * ss[64 + lane];
        #pragma unroll
        for (int off = 32; off > 0; off >>= 1)
            p += __shfl_down(p, off, 64);
        if (lane == 0) {
            denom[(size_t)bh * PN + n0 + r] = (p < 1e-12f) ? 1e-12f : p;
        }
    }
}

// ---------------- out_head[b,n,h*64+d] = (qf . kv[:,d]) / denom ----------------
// grid B*H*32 (32 rows per block); 256 threads: d = t&63, row group = t>>6 (8 rows each).
__global__ __launch_bounds__(256) void apply_kernel(
        const float* __restrict__ qf, const float* __restrict__ kv,
        const float* __restrict__ denom, float* __restrict__ oh)
{
    __shared__ float kvs[128][64];
    __shared__ float qfs[32][128];
    __shared__ float dns[32];
    const int t = threadIdx.x;
    const int bh = blockIdx.x >> 5;
    const int n0 = (blockIdx.x & 31) * 32;
    const int b = bh / PH, h = bh % PH;
    const float* kvb = kv + (size_t)bh * PM * PD;
    #pragma unroll
    for (int i = 0; i < 32; ++i) {
        int idx = i * 256 + t;
        kvs[idx >> 6][idx & 63] = kvb[idx];
    }
    const float* qfb = qf + ((size_t)bh * PN + n0) * PM;
    #pragma unroll
    for (int i = 0; i < 16; ++i) {
        int idx = i * 256 + t;
        qfs[idx >> 7][idx & 127] = qfb[idx];
    }
    if (t < 32) dns[t] = denom[(size_t)bh * PN + n0 + t];
    __syncthreads();
    const int d = t & 63, rg = t >> 6;
    float acc[8] = {0.f};
    for (int mm = 0; mm < 128; ++mm) {
        float kvv = kvs[mm][d];
        #pragma unroll
        for (int j = 0; j < 8; ++j)
            acc[j] += qfs[rg * 8 + j][mm] * kvv;
    }
    float* ob = oh + ((size_t)(b * PN + n0) * PC) + h * PD + d;
    #pragma unroll
    for (int j = 0; j < 8; ++j) {
        int r = rg * 8 + j;
        ob[(size_t)r * PC] = acc[j] / dns[r];
    }
}

extern "C" void kernel_launch(void* const* d_in, const int* in_sizes, int n_in,
                              void* d_out, int out_size, void* d_ws, size_t ws_size,
                              hipStream_t stream) {
    const float* x      = (const float*)d_in[0];  // [B,N,C]
    const float* qkv_w  = (const float*)d_in[1];  // [3C,C]
    const float* proj_w = (const float*)d_in[2];  // [C,C]
    const float* proj_b = (const float*)d_in[3];  // [C]
    const float* rm     = (const float*)d_in[4];  // [H,D,M]
    float* out = (float*)d_out;                    // [B,N,C]

    float* ws  = (float*)d_ws;
    float* qkv = ws;                               // 8192*2304 = 18,874,368
    float* qf  = qkv + (size_t)8192 * 2304;        // 12,582,912
    float* kf  = qf + (size_t)PB * PH * PN * PM;   // 12,582,912
    float* kv  = kf + (size_t)PB * PH * PN * PM;   // 786,432
    float* s   = kv + (size_t)PB * PH * PM * PD;   // 12,288
    float* dn  = s + (size_t)PB * PH * PM;         // 98,304
    float* oh  = dn + (size_t)PB * PH * PN;        // 6,291,456

    // 1) qkv = x @ qkv_w^T  : [8192,768] x [2304,768]^T -> [8192,2304]
    gemm_nt_bias<<<dim3(2304 / 64, 8192 / 64), 256, 0, stream>>>(
        x, qkv_w, qkv, 8192, 2304, 768, nullptr);

    // 2) feature maps for q and k
    feat_map<<<dim3(PB * PH * (PN / 16), 2), 128, 0, stream>>>(qkv, rm, qf, kf);

    // 3) KV = kf^T @ v, s = colsum(kf)
    kv_s_kernel<<<dim3(PB * PH, PD / 8), 256, 0, stream>>>(qkv, kf, kv, s);

    // 4) denom
    denom_kernel<<<PB * PH * 16, 256, 0, stream>>>(qf, s, dn);

    // 5) apply: oh[b,n,c] laid out for final GEMM
    apply_kernel<<<PB * PH * 32, 256, 0, stream>>>(qf, kv, dn, oh);

    // 6) out = oh @ proj_w^T + proj_b
    gemm_nt_bias<<<dim3(PC / 64, 8192 / 64), 256, 0, stream>>>(
        oh, proj_w, out, 8192, PC, 768, proj_b);
}

// Round 2
// 524.323 us; speedup vs baseline: 1.6088x; 1.6088x over previous
//
#include <hip/hip_runtime.h>
#include <hip/hip_bf16.h>

// Problem constants: B=8, N=1024, C=768, H=12, D=64, M=128
#define PB 8
#define PN 1024
#define PC 768
#define PH 12
#define PD 64
#define PM 128
#define SQ 0.35355339059327373f      // (D^-0.5)^0.5
#define MSCALE 0.08838834764831843f  // M^-0.5

typedef _Float16 f16;
typedef f16 f16x8 __attribute__((ext_vector_type(8)));
typedef f16 f16x4 __attribute__((ext_vector_type(4)));
typedef float f32x4 __attribute__((ext_vector_type(4)));

// ---------------- conversion kernels: fp32 -> split f16 ----------------
// A-side: dst[r][c]=hi, dst[r][cols+c]=lo   (row stride 2*cols)
__global__ __launch_bounds__(192) void split_a2(const float* __restrict__ src,
                                                f16* __restrict__ dst, int cols) {
    const int r = blockIdx.x;
    const int c = threadIdx.x * 4;
    float4 v = *(const float4*)&src[(size_t)r * cols + c];
    f16x4 hi, lo;
    hi.x = (f16)v.x; lo.x = (f16)(v.x - (float)hi.x);
    hi.y = (f16)v.y; lo.y = (f16)(v.y - (float)hi.y);
    hi.z = (f16)v.z; lo.z = (f16)(v.z - (float)hi.z);
    hi.w = (f16)v.w; lo.w = (f16)(v.w - (float)hi.w);
    f16* d = dst + (size_t)r * 2 * cols;
    *(f16x4*)&d[c] = hi;
    *(f16x4*)&d[cols + c] = lo;
}

// B-side: dst[r][c]=hi, dst[r][cols+c]=hi, dst[r][2*cols+c]=lo  (row stride 3*cols)
__global__ __launch_bounds__(192) void split_b3(const float* __restrict__ src,
                                                f16* __restrict__ dst, int cols) {
    const int r = blockIdx.x;
    const int c = threadIdx.x * 4;
    float4 v = *(const float4*)&src[(size_t)r * cols + c];
    f16x4 hi, lo;
    hi.x = (f16)v.x; lo.x = (f16)(v.x - (float)hi.x);
    hi.y = (f16)v.y; lo.y = (f16)(v.y - (float)hi.y);
    hi.z = (f16)v.z; lo.z = (f16)(v.z - (float)hi.z);
    hi.w = (f16)v.w; lo.w = (f16)(v.w - (float)hi.w);
    f16* d = dst + (size_t)r * 3 * cols;
    *(f16x4*)&d[c] = hi;
    *(f16x4*)&d[cols + c] = hi;
    *(f16x4*)&d[2 * cols + c] = lo;
}

// plain hi only (row stride cols)
__global__ __launch_bounds__(192) void conv_hi(const float* __restrict__ src,
                                               f16* __restrict__ dst, int cols) {
    const int r = blockIdx.x;
    const int c = threadIdx.x * 4;
    float4 v = *(const float4*)&src[(size_t)r * cols + c];
    f16x4 hi;
    hi.x = (f16)v.x; hi.y = (f16)v.y; hi.z = (f16)v.z; hi.w = (f16)v.w;
    *(f16x4*)&dst[(size_t)r * cols + c] = hi;
}

// ---------------- MFMA GEMM: C[i,j] = sum_k A[i,ka]*B[j,k] (+bias) ----------------
// 128x128 tile, BK=32, 4 waves (2x2), mfma_f32_16x16x32_f16, global_load_lds x16.
// A k-index wraps at wrapA (so A' stores only [hi,lo] while K'=3K).
__global__ __launch_bounds__(256) void gemm_mfma(
        const f16* __restrict__ A, int lda, int wrapA,
        const f16* __restrict__ Bm, int ldb,
        float* __restrict__ Cm, int ldc, int colOff, int Kp,
        const float* __restrict__ bias)
{
    __shared__ f16 As[128 * 32];
    __shared__ f16 Bs[128 * 32];
    const int t = threadIdx.x;
    const int wave = t >> 6, lane = t & 63;
    const int wm = wave >> 1, wn = wave & 1;
    const int bi = blockIdx.y * 128, bj = blockIdx.x * 128;

    f32x4 acc[4][4] = {};

    // staging: wave covers 32 rows of each tile via 2 x 16-row async loads
    const int srow = wave * 32 + (lane >> 2);
    const int scol = (lane & 3) * 8;
    const f16* Ap = A + (size_t)(bi + srow) * lda + scol;
    const f16* Bp = Bm + (size_t)(bj + srow) * ldb + scol;
    f16* AsB = &As[wave * 32 * 32];
    f16* BsB = &Bs[wave * 32 * 32];

    const int nK = Kp / 32;
    for (int kt = 0; kt < nK; ++kt) {
        const int k0 = kt * 32;
        const int ka = (k0 >= wrapA) ? k0 - wrapA : k0;
        __syncthreads();
        __builtin_amdgcn_global_load_lds(
            (const __attribute__((address_space(1))) void*)(Ap + ka),
            (__attribute__((address_space(3))) void*)(AsB), 16, 0, 0);
        __builtin_amdgcn_global_load_lds(
            (const __attribute__((address_space(1))) void*)(Ap + ka + (size_t)16 * lda),
            (__attribute__((address_space(3))) void*)(AsB + 16 * 32), 16, 0, 0);
        __builtin_amdgcn_global_load_lds(
            (const __attribute__((address_space(1))) void*)(Bp + k0),
            (__attribute__((address_space(3))) void*)(BsB), 16, 0, 0);
        __builtin_amdgcn_global_load_lds(
            (const __attribute__((address_space(1))) void*)(Bp + k0 + (size_t)16 * ldb),
            (__attribute__((address_space(3))) void*)(BsB + 16 * 32), 16, 0, 0);
        __syncthreads();

        f16x8 af[4], bf[4];
        #pragma unroll
        for (int i = 0; i < 4; ++i)
            af[i] = *(const f16x8*)&As[(wm * 64 + i * 16 + (lane & 15)) * 32 + (lane >> 4) * 8];
        #pragma unroll
        for (int j = 0; j < 4; ++j)
            bf[j] = *(const f16x8*)&Bs[(wn * 64 + j * 16 + (lane & 15)) * 32 + (lane >> 4) * 8];
        #pragma unroll
        for (int i = 0; i < 4; ++i)
            #pragma unroll
            for (int j = 0; j < 4; ++j)
                acc[i][j] = __builtin_amdgcn_mfma_f32_16x16x32_f16(af[i], bf[j], acc[i][j], 0, 0, 0);
    }

    // epilogue: D row = quad*4+reg, col = lane&15
    const int cr = (lane >> 4) * 4, cc = lane & 15;
    #pragma unroll
    for (int i = 0; i < 4; ++i) {
        const int row = bi + wm * 64 + i * 16 + cr;
        #pragma unroll
        for (int j = 0; j < 4; ++j) {
            const int col = bj + wn * 64 + j * 16 + cc;
            const float bv = bias ? bias[col] : 0.f;
            #pragma unroll
            for (int r = 0; r < 4; ++r)
                Cm[(size_t)(row + r) * ldc + colOff + col] = acc[i][j][r] + bv;
        }
    }
}

// ---------------- Feature map: qf/kf = exp(z@R[h] - 0.5|z|^2) * M^-0.5 ----------------
// grid = B*H*(N/32); 256 thr: m = t&127, which = t>>7 (0=q,1=k). R column in registers.
__global__ __launch_bounds__(256) void feat_map(
        const float* __restrict__ qkv, const float* __restrict__ rm,
        float* __restrict__ qf, float* __restrict__ kf)
{
    __shared__ float zs[2][32][64];
    __shared__ float sqn[2][32];
    const int t = threadIdx.x;
    int bx = blockIdx.x;
    const int chunk = bx & 31; bx >>= 5;
    const int h = bx % PH, b = bx / PH;
    const int n0 = chunk * 32;
    const int m = t & 127, wh = t >> 7;

    float Rr[64];
    const float* rh = rm + (size_t)h * PD * PM + m;
    #pragma unroll
    for (int d = 0; d < 64; ++d) Rr[d] = rh[d * PM];

    const float* qb = qkv + (size_t)(b * PN + n0) * (3 * PC) + h * PD;
    #pragma unroll
    for (int i = 0; i < 16; ++i) {
        int idx = i * 256 + t;                 // 0..4095
        int w = idx >> 11, row = (idx >> 6) & 31, d = idx & 63;
        zs[w][row][d] = qb[(size_t)row * (3 * PC) + w * PC + d] * SQ;
    }
    __syncthreads();
    if (t < 64) {
        int w = t >> 5, row = t & 31;
        float s2 = 0.f;
        #pragma unroll
        for (int d = 0; d < 64; ++d) { float z = zs[w][row][d]; s2 += z * z; }
        sqn[w][row] = 0.5f * s2;
    }
    __syncthreads();

    float* op = (wh ? kf : qf) + ((size_t)((b * PH + h) * PN + n0)) * PM + m;
    for (int r = 0; r < 32; ++r) {
        float logit = 0.f;
        #pragma unroll
        for (int d4 = 0; d4 < 16; ++d4) {
            float4 z = *(const float4*)&zs[wh][r][d4 * 4];
            logit += z.x * Rr[4 * d4] + z.y * Rr[4 * d4 + 1]
                   + z.z * Rr[4 * d4 + 2] + z.w * Rr[4 * d4 + 3];
        }
        op[(size_t)r * PM] = __expf(logit - sqn[wh][r]) * MSCALE;
    }
}

// ---------------- KV = kf^T @ v (partials over n-halves), s = colsum(kf) ----------------
// grid (B*H, 2 d-halves, 2 n-halves); 256 thr: m=t&127, 16 d's per thread.
__global__ __launch_bounds__(256) void kv_s_kernel(
        const float* __restrict__ qkv, const float* __restrict__ kf,
        float* __restrict__ kvp, float* __restrict__ sbuf)
{
    __shared__ float kfs[64][128];
    __shared__ float vs[64][32];
    const int t = threadIdx.x;
    const int bh = blockIdx.x;
    const int b = bh / PH, h = bh % PH;
    const int d0 = blockIdx.y * 32;
    const int nh = blockIdx.z;
    const int nbase = nh * 512;
    const int m = t & 127;
    const int dsub = (t >> 7) * 16;
    float acc[16];
    #pragma unroll
    for (int j = 0; j < 16; ++j) acc[j] = 0.f;
    float sacc = 0.f;
    const float* kfb = kf + (size_t)bh * PN * PM;
    const float* vb  = qkv + (size_t)b * PN * (3 * PC) + 2 * PC + h * PD + d0;
    for (int n0 = nbase; n0 < nbase + 512; n0 += 64) {
        #pragma unroll
        for (int i = 0; i < 32; ++i) {
            int idx = i * 256 + t;
            kfs[idx >> 7][idx & 127] = kfb[(size_t)(n0 + (idx >> 7)) * PM + (idx & 127)];
        }
        #pragma unroll
        for (int i = 0; i < 8; ++i) {
            int idx = i * 256 + t;
            vs[idx >> 5][idx & 31] = vb[(size_t)(n0 + (idx >> 5)) * (3 * PC) + (idx & 31)];
        }
        __syncthreads();
        #pragma unroll 4
        for (int nn = 0; nn < 64; ++nn) {
            float kq = kfs[nn][m];
            sacc += kq;
            #pragma unroll
            for (int j = 0; j < 16; ++j)
                acc[j] += kq * vs[nn][dsub + j];
        }
        __syncthreads();
    }
    float* kvo = kvp + (((size_t)(nh * 96 + bh) * PM + m)) * PD + d0 + dsub;
    #pragma unroll
    for (int j = 0; j < 16; ++j) kvo[j] = acc[j];
    if (blockIdx.y == 0 && dsub == 0)
        sbuf[(size_t)(nh * 96 + bh) * PM + m] = sacc;
}

// ---------------- apply: oh = (qf @ KV) / (qf . s), written as split-f16 [hi,lo] ----------------
// grid B*H*32 (32 rows/block); 256 thr: d = t&63, row group = t>>6 (8 rows each).
__global__ __launch_bounds__(256) void apply_kernel(
        const float* __restrict__ qf, const float* __restrict__ kvp,
        const float* __restrict__ sbuf, f16* __restrict__ ohA)
{
    __shared__ float kvs[128][64];
    __shared__ float qfs[32][128];
    __shared__ float ss[128];
    __shared__ float part[32][8];
    __shared__ float dns[32];
    const int t = threadIdx.x;
    const int bh = blockIdx.x >> 5;
    const int n0 = (blockIdx.x & 31) * 32;
    const int b = bh / PH, h = bh % PH;

    const float* kv0 = kvp + (size_t)bh * PM * PD;
    const float* kv1 = kvp + (size_t)(96 + bh) * PM * PD;
    #pragma unroll
    for (int i = 0; i < 32; ++i) {
        int idx = i * 256 + t;
        kvs[idx >> 6][idx & 63] = kv0[idx] + kv1[idx];
    }
    const float* qfb = qf + ((size_t)bh * PN + n0) * PM;
    #pragma unroll
    for (int i = 0; i < 16; ++i) {
        int idx = i * 256 + t;
        qfs[idx >> 7][idx & 127] = qfb[idx];
    }
    if (t < 128) ss[t] = sbuf[(size_t)bh * PM + t] + sbuf[(size_t)(96 + bh) * PM + t];
    __syncthreads();
    {   // denominator: 8 segments of 16 m's per row
        const int row = t & 31, seg = t >> 5;
        float p = 0.f;
        #pragma unroll
        for (int mm = seg * 16; mm < seg * 16 + 16; ++mm)
            p += qfs[row][mm] * ss[mm];
        part[row][seg] = p;
    }
    __syncthreads();
    if (t < 32) {
        float dsum = 0.f;
        #pragma unroll
        for (int j = 0; j < 8; ++j) dsum += part[t][j];
        dns[t] = (dsum < 1e-12f) ? 1e-12f : dsum;
    }
    __syncthreads();

    const int d = t & 63, rg = t >> 6;
    float acc[8] = {0.f};
    for (int mm = 0; mm < 128; ++mm) {
        float kvv = kvs[mm][d];
        #pragma unroll
        for (int j = 0; j < 8; ++j)
            acc[j] += qfs[rg * 8 + j][mm] * kvv;
    }
    f16* ob = ohA + (size_t)(b * PN + n0) * 1536 + h * PD + d;
    #pragma unroll
    for (int j = 0; j < 8; ++j) {
        const int r = rg * 8 + j;
        float v = acc[j] / dns[r];
        f16 hi = (f16)v;
        f16 lo = (f16)(v - (float)hi);
        ob[(size_t)r * 1536] = hi;
        ob[(size_t)r * 1536 + PC] = lo;
    }
}

extern "C" void kernel_launch(void* const* d_in, const int* in_sizes, int n_in,
                              void* d_out, int out_size, void* d_ws, size_t ws_size,
                              hipStream_t stream) {
    const float* x      = (const float*)d_in[0];  // [B,N,C]
    const float* qkv_w  = (const float*)d_in[1];  // [3C,C]
    const float* proj_w = (const float*)d_in[2];  // [C,C]
    const float* proj_b = (const float*)d_in[3];  // [C]
    const float* rm     = (const float*)d_in[4];  // [H,D,M]
    float* out = (float*)d_out;                    // [B,N,C]

    char* ws = (char*)d_ws;
    // region layout (bytes), total 201.3 MB (round-1 proved >= 204 MB available)
    float* qkv = (float*)(ws);                          // 75,497,472  [8192][2304] f32
    float* qf  = (float*)(ws + 75497472);               // 50,331,648  [96][1024][128] f32
    float* kf  = (float*)(ws + 125829120);              // 50,331,648
    f16*   Asp = (f16*)(ws + 176160768);                // 25,165,824  [8192][1536] f16 (hi,lo)
    // sub-regions reusing qf (dead until feat_map runs):
    f16* Bqk = (f16*)(ws + 75497472);                   // [1536][2304] f16 = 7,077,888
    f16* Bv  = (f16*)(ws + 75497472 + 7077888);         // [768][768]  f16 = 1,179,648
    // sub-regions reusing Asp's space (dead after v-gemm):
    f16*   Bp   = (f16*)(ws + 176160768);               // [768][2304] f16 = 3,538,944
    float* kvp  = (float*)(ws + 176160768 + 3538944);   // [2][96][128][64] f32 = 6,291,456
    float* sbuf = (float*)(ws + 176160768 + 9830400);   // [2][96][128] f32 = 98,304
    // ohA reuses kf region (kf dead after kv_s):
    f16* ohA = (f16*)(ws + 125829120);                  // [8192][1536] f16 = 25,165,824

    // 1) conversions
    split_a2<<<8192, 192, 0, stream>>>(x, Asp, PC);
    split_b3<<<1536, 192, 0, stream>>>(qkv_w, Bqk, PC);
    conv_hi <<<768, 192, 0, stream>>>(qkv_w + (size_t)1536 * PC, Bv, PC);

    // 2) q,k projection: [8192][1536] = Asp(wrap 1536) x Bqk, K'=2304
    gemm_mfma<<<dim3(12, 64), 256, 0, stream>>>(Asp, 1536, 1536, Bqk, 2304,
                                                qkv, 2304, 0, 2304, nullptr);
    // 3) v projection: plain f16, K=768
    gemm_mfma<<<dim3(6, 64), 256, 0, stream>>>(Asp, 1536, 1 << 30, Bv, 768,
                                               qkv, 2304, 1536, 768, nullptr);
    // 4) proj weights conversion (into Asp region tail usage is safe now)
    split_b3<<<768, 192, 0, stream>>>(proj_w, Bp, PC);

    // 5) feature maps (overwrites qf/kf regions incl. Bqk/Bv)
    feat_map<<<PB * PH * (PN / 32), 256, 0, stream>>>(qkv, rm, qf, kf);

    // 6) KV partials + s partials
    kv_s_kernel<<<dim3(96, 2, 2), 256, 0, stream>>>(qkv, kf, kvp, sbuf);

    // 7) apply + fused denom, writes split-f16 oh (into kf region)
    apply_kernel<<<96 * 32, 256, 0, stream>>>(qf, kvp, sbuf, ohA);

    // 8) out = oh @ proj_w^T + proj_b : K'=2304 with A-wrap at 1536
    gemm_mfma<<<dim3(6, 64), 256, 0, stream>>>(ohA, 1536, 1536, Bp, 2304,
                                               out, 768, 0, 2304, proj_b);
}

// Round 3
// 430.290 us; speedup vs baseline: 1.9603x; 1.2185x over previous
//
#include <hip/hip_runtime.h>
#include <hip/hip_bf16.h>

// Problem constants: B=8, N=1024, C=768, H=12, D=64, M=128
#define PB 8
#define PN 1024
#define PC 768
#define PH 12
#define PD 64
#define PM 128
#define SQ 0.35355339059327373f      // (D^-0.5)^0.5
#define MSCALE 0.08838834764831843f  // M^-0.5

typedef _Float16 f16;
typedef f16 f16x8 __attribute__((ext_vector_type(8)));
typedef f16 f16x4 __attribute__((ext_vector_type(4)));
typedef float f32x4 __attribute__((ext_vector_type(4)));

// ---------------- conversion kernels: fp32 -> split f16 ----------------
__global__ __launch_bounds__(192) void split_a2(const float* __restrict__ src,
                                                f16* __restrict__ dst, int cols) {
    const int r = blockIdx.x;
    const int c = threadIdx.x * 4;
    float4 v = *(const float4*)&src[(size_t)r * cols + c];
    f16x4 hi, lo;
    hi.x = (f16)v.x; lo.x = (f16)(v.x - (float)hi.x);
    hi.y = (f16)v.y; lo.y = (f16)(v.y - (float)hi.y);
    hi.z = (f16)v.z; lo.z = (f16)(v.z - (float)hi.z);
    hi.w = (f16)v.w; lo.w = (f16)(v.w - (float)hi.w);
    f16* d = dst + (size_t)r * 2 * cols;
    *(f16x4*)&d[c] = hi;
    *(f16x4*)&d[cols + c] = lo;
}

__global__ __launch_bounds__(192) void split_b3(const float* __restrict__ src,
                                                f16* __restrict__ dst, int cols) {
    const int r = blockIdx.x;
    const int c = threadIdx.x * 4;
    float4 v = *(const float4*)&src[(size_t)r * cols + c];
    f16x4 hi, lo;
    hi.x = (f16)v.x; lo.x = (f16)(v.x - (float)hi.x);
    hi.y = (f16)v.y; lo.y = (f16)(v.y - (float)hi.y);
    hi.z = (f16)v.z; lo.z = (f16)(v.z - (float)hi.z);
    hi.w = (f16)v.w; lo.w = (f16)(v.w - (float)hi.w);
    f16* d = dst + (size_t)r * 3 * cols;
    *(f16x4*)&d[c] = hi;
    *(f16x4*)&d[cols + c] = hi;
    *(f16x4*)&d[2 * cols + c] = lo;
}

__global__ __launch_bounds__(192) void conv_hi(const float* __restrict__ src,
                                               f16* __restrict__ dst, int cols) {
    const int r = blockIdx.x;
    const int c = threadIdx.x * 4;
    float4 v = *(const float4*)&src[(size_t)r * cols + c];
    f16x4 hi;
    hi.x = (f16)v.x; hi.y = (f16)v.y; hi.z = (f16)v.z; hi.w = (f16)v.w;
    *(f16x4*)&dst[(size_t)r * cols + c] = hi;
}

// ---------------- MFMA GEMM: C[i,j] = sum_k A[i,ka]*B[j,k] (+bias) ----------------
// 128x128 tile, BK=32, 4 waves (2x2), mfma_f32_16x16x32_f16, global_load_lds x16.
__global__ __launch_bounds__(256) void gemm_mfma(
        const f16* __restrict__ A, int lda, int wrapA,
        const f16* __restrict__ Bm, int ldb,
        float* __restrict__ Cm, int ldc, int colOff, int Kp,
        const float* __restrict__ bias)
{
    __shared__ f16 As[128 * 32];
    __shared__ f16 Bs[128 * 32];
    const int t = threadIdx.x;
    const int wave = t >> 6, lane = t & 63;
    const int wm = wave >> 1, wn = wave & 1;
    const int bi = blockIdx.y * 128, bj = blockIdx.x * 128;

    f32x4 acc[4][4] = {};

    const int srow = wave * 32 + (lane >> 2);
    const int scol = (lane & 3) * 8;
    const f16* Ap = A + (size_t)(bi + srow) * lda + scol;
    const f16* Bp = Bm + (size_t)(bj + srow) * ldb + scol;
    f16* AsB = &As[wave * 32 * 32];
    f16* BsB = &Bs[wave * 32 * 32];

    const int nK = Kp / 32;
    for (int kt = 0; kt < nK; ++kt) {
        const int k0 = kt * 32;
        const int ka = (k0 >= wrapA) ? k0 - wrapA : k0;
        __syncthreads();
        __builtin_amdgcn_global_load_lds(
            (const __attribute__((address_space(1))) void*)(Ap + ka),
            (__attribute__((address_space(3))) void*)(AsB), 16, 0, 0);
        __builtin_amdgcn_global_load_lds(
            (const __attribute__((address_space(1))) void*)(Ap + ka + (size_t)16 * lda),
            (__attribute__((address_space(3))) void*)(AsB + 16 * 32), 16, 0, 0);
        __builtin_amdgcn_global_load_lds(
            (const __attribute__((address_space(1))) void*)(Bp + k0),
            (__attribute__((address_space(3))) void*)(BsB), 16, 0, 0);
        __builtin_amdgcn_global_load_lds(
            (const __attribute__((address_space(1))) void*)(Bp + k0 + (size_t)16 * ldb),
            (__attribute__((address_space(3))) void*)(BsB + 16 * 32), 16, 0, 0);
        __syncthreads();

        f16x8 af[4], bf[4];
        #pragma unroll
        for (int i = 0; i < 4; ++i)
            af[i] = *(const f16x8*)&As[(wm * 64 + i * 16 + (lane & 15)) * 32 + (lane >> 4) * 8];
        #pragma unroll
        for (int j = 0; j < 4; ++j)
            bf[j] = *(const f16x8*)&Bs[(wn * 64 + j * 16 + (lane & 15)) * 32 + (lane >> 4) * 8];
        #pragma unroll
        for (int i = 0; i < 4; ++i)
            #pragma unroll
            for (int j = 0; j < 4; ++j)
                acc[i][j] = __builtin_amdgcn_mfma_f32_16x16x32_f16(af[i], bf[j], acc[i][j], 0, 0, 0);
    }

    const int cr = (lane >> 4) * 4, cc = lane & 15;
    #pragma unroll
    for (int i = 0; i < 4; ++i) {
        const int row = bi + wm * 64 + i * 16 + cr;
        #pragma unroll
        for (int j = 0; j < 4; ++j) {
            const int col = bj + wn * 64 + j * 16 + cc;
            const float bv = bias ? bias[col] : 0.f;
            #pragma unroll
            for (int r = 0; r < 4; ++r)
                Cm[(size_t)(row + r) * ldc + colOff + col] = acc[i][j][r] + bv;
        }
    }
}

// ---------------- Feature map ----------------
__global__ __launch_bounds__(256) void feat_map(
        const float* __restrict__ qkv, const float* __restrict__ rm,
        float* __restrict__ qf, float* __restrict__ kf)
{
    __shared__ float zs[2][32][64];
    __shared__ float sqn[2][32];
    const int t = threadIdx.x;
    int bx = blockIdx.x;
    const int chunk = bx & 31; bx >>= 5;
    const int h = bx % PH, b = bx / PH;
    const int n0 = chunk * 32;
    const int m = t & 127, wh = t >> 7;

    float Rr[64];
    const float* rh = rm + (size_t)h * PD * PM + m;
    #pragma unroll
    for (int d = 0; d < 64; ++d) Rr[d] = rh[d * PM];

    const float* qb = qkv + (size_t)(b * PN + n0) * (3 * PC) + h * PD;
    #pragma unroll
    for (int i = 0; i < 16; ++i) {
        int idx = i * 256 + t;
        int w = idx >> 11, row = (idx >> 6) & 31, d = idx & 63;
        zs[w][row][d] = qb[(size_t)row * (3 * PC) + w * PC + d] * SQ;
    }
    __syncthreads();
    if (t < 64) {
        int w = t >> 5, row = t & 31;
        float s2 = 0.f;
        #pragma unroll
        for (int d = 0; d < 64; ++d) { float z = zs[w][row][d]; s2 += z * z; }
        sqn[w][row] = 0.5f * s2;
    }
    __syncthreads();

    float* op = (wh ? kf : qf) + ((size_t)((b * PH + h) * PN + n0)) * PM + m;
    for (int r = 0; r < 32; ++r) {
        float logit = 0.f;
        #pragma unroll
        for (int d4 = 0; d4 < 16; ++d4) {
            float4 z = *(const float4*)&zs[wh][r][d4 * 4];
            logit += z.x * Rr[4 * d4] + z.y * Rr[4 * d4 + 1]
                   + z.z * Rr[4 * d4 + 2] + z.w * Rr[4 * d4 + 3];
        }
        op[(size_t)r * PM] = __expf(logit - sqn[wh][r]) * MSCALE;
    }
}

// ---------------- KV partials over 8 n-chunks, s partials ----------------
// grid (96, 8); 256 thr: m = t&127, d-half = t>>7 (32 d's each). kf read coalesced
// directly from global (no staging); v (32 KB) in LDS, broadcast reads.
__global__ __launch_bounds__(256) void kv_s_kernel(
        const float* __restrict__ qkv, const float* __restrict__ kf,
        float* __restrict__ kvp, float* __restrict__ sbufp)
{
    __shared__ float vs[128][64];
    const int t = threadIdx.x;
    const int bh = blockIdx.x;
    const int nc = blockIdx.y;
    const int n0 = nc * 128;
    const int b = bh / PH, h = bh % PH;
    const int m = t & 127, dh = t >> 7;

    const float* vb = qkv + (size_t)b * PN * (3 * PC) + 2 * PC + h * PD;
    #pragma unroll
    for (int i = 0; i < 32; ++i) {
        int idx = i * 256 + t;
        int row = idx >> 6, d = idx & 63;
        vs[row][d] = vb[(size_t)(n0 + row) * (3 * PC) + d];
    }
    __syncthreads();

    float acc[32];
    #pragma unroll
    for (int j = 0; j < 32; ++j) acc[j] = 0.f;
    float sacc = 0.f;
    const float* kfb = kf + ((size_t)bh * PN + n0) * PM + m;
    #pragma unroll 8
    for (int nn = 0; nn < 128; ++nn) {
        float kq = kfb[(size_t)nn * PM];
        sacc += kq;
        #pragma unroll
        for (int j = 0; j < 32; ++j)
            acc[j] += kq * vs[nn][dh * 32 + j];
    }

    float* kvo = kvp + (((size_t)(nc * 96 + bh) * PM + m)) * PD + dh * 32;
    #pragma unroll
    for (int j = 0; j < 32; ++j) kvo[j] = acc[j];
    if (dh == 0)
        sbufp[(size_t)(nc * 96 + bh) * PM + m] = sacc;
}

// ---------------- reduce 8 kv/s partials ----------------
__global__ __launch_bounds__(256) void kv_reduce(
        const float* __restrict__ kvp, const float* __restrict__ sbufp,
        float* __restrict__ kv, float* __restrict__ s)
{
    const int idx = blockIdx.x * 256 + threadIdx.x;  // 0..786431
    float a = 0.f;
    #pragma unroll
    for (int c = 0; c < 8; ++c) a += kvp[(size_t)c * 786432 + idx];
    kv[idx] = a;
    if (idx < 96 * PM) {
        float sa = 0.f;
        #pragma unroll
        for (int c = 0; c < 8; ++c) sa += sbufp[(size_t)c * 96 * PM + idx];
        s[idx] = sa;
    }
}

// ---------------- apply: oh = (qf @ KV) / (qf . s), split-f16 out ----------------
__global__ __launch_bounds__(256) void apply_kernel(
        const float* __restrict__ qf, const float* __restrict__ kv,
        const float* __restrict__ sv, f16* __restrict__ ohA)
{
    __shared__ float kvs[128][64];
    __shared__ float qfs[32][128];
    __shared__ float ss[128];
    __shared__ float part[32][8];
    __shared__ float dns[32];
    const int t = threadIdx.x;
    const int bh = blockIdx.x >> 5;
    const int n0 = (blockIdx.x & 31) * 32;
    const int b = bh / PH, h = bh % PH;

    const float* kv0 = kv + (size_t)bh * PM * PD;
    #pragma unroll
    for (int i = 0; i < 32; ++i) {
        int idx = i * 256 + t;
        kvs[idx >> 6][idx & 63] = kv0[idx];
    }
    const float* qfb = qf + ((size_t)bh * PN + n0) * PM;
    #pragma unroll
    for (int i = 0; i < 16; ++i) {
        int idx = i * 256 + t;
        qfs[idx >> 7][idx & 127] = qfb[idx];
    }
    if (t < 128) ss[t] = sv[(size_t)bh * PM + t];
    __syncthreads();
    {
        const int row = t & 31, seg = t >> 5;
        float p = 0.f;
        #pragma unroll
        for (int mm = seg * 16; mm < seg * 16 + 16; ++mm)
            p += qfs[row][mm] * ss[mm];
        part[row][seg] = p;
    }
    __syncthreads();
    if (t < 32) {
        float dsum = 0.f;
        #pragma unroll
        for (int j = 0; j < 8; ++j) dsum += part[t][j];
        dns[t] = (dsum < 1e-12f) ? 1e-12f : dsum;
    }
    __syncthreads();

    const int d = t & 63, rg = t >> 6;
    float acc[8] = {0.f};
    for (int mm = 0; mm < 128; ++mm) {
        float kvv = kvs[mm][d];
        #pragma unroll
        for (int j = 0; j < 8; ++j)
            acc[j] += qfs[rg * 8 + j][mm] * kvv;
    }
    f16* ob = ohA + (size_t)(b * PN + n0) * 1536 + h * PD + d;
    #pragma unroll
    for (int j = 0; j < 8; ++j) {
        const int r = rg * 8 + j;
        float v = acc[j] / dns[r];
        f16 hi = (f16)v;
        f16 lo = (f16)(v - (float)hi);
        ob[(size_t)r * 1536] = hi;
        ob[(size_t)r * 1536 + PC] = lo;
    }
}

extern "C" void kernel_launch(void* const* d_in, const int* in_sizes, int n_in,
                              void* d_out, int out_size, void* d_ws, size_t ws_size,
                              hipStream_t stream) {
    const float* x      = (const float*)d_in[0];  // [B,N,C]
    const float* qkv_w  = (const float*)d_in[1];  // [3C,C]
    const float* proj_w = (const float*)d_in[2];  // [C,C]
    const float* proj_b = (const float*)d_in[3];  // [C]
    const float* rm     = (const float*)d_in[4];  // [H,D,M]
    float* out = (float*)d_out;                    // [B,N,C] = 25,165,824 B

    char* ws = (char*)d_ws;
    float* qkv = (float*)(ws);                          // 75,497,472  [8192][2304] f32
    float* qf  = (float*)(ws + 75497472);               // 50,331,648  [96][1024][128] f32
    float* kf  = (float*)(ws + 125829120);              // 50,331,648
    f16*   Asp = (f16*)(ws + 176160768);                // 25,165,824  [8192][1536] f16 (hi,lo)
    // overlays:
    f16* Bqk = (f16*)(ws + 75497472);                   // in qf region (dead pre-feat_map)
    f16* Bv  = (f16*)(ws + 75497472 + 7077888);
    f16*   Bp   = (f16*)(ws + 176160768);               // in Asp region (dead post v-gemm)
    float* sbufp = (float*)(ws + 176160768 + 3538944);  // [8][96][128] f32 = 393,216
    float* kvf   = (float*)(ws + 176160768 + 3932160);  // [96][128][64] f32 = 3,145,728
    float* sf    = (float*)(ws + 176160768 + 7077888);  // [96][128] f32 = 49,152
    // kv partials live in d_out (dead until final gemm): [8][96][128][64] f32 = 25,165,824
    float* kvp = (float*)d_out;
    // ohA overlays kf (dead after kv_s)
    f16* ohA = (f16*)(ws + 125829120);

    // 1) conversions
    split_a2<<<8192, 192, 0, stream>>>(x, Asp, PC);
    split_b3<<<1536, 192, 0, stream>>>(qkv_w, Bqk, PC);
    conv_hi <<<768, 192, 0, stream>>>(qkv_w + (size_t)1536 * PC, Bv, PC);

    // 2) q,k projection
    gemm_mfma<<<dim3(12, 64), 256, 0, stream>>>(Asp, 1536, 1536, Bqk, 2304,
                                                qkv, 2304, 0, 2304, nullptr);
    // 3) v projection
    gemm_mfma<<<dim3(6, 64), 256, 0, stream>>>(Asp, 1536, 1 << 30, Bv, 768,
                                               qkv, 2304, 1536, 768, nullptr);
    // 4) proj weights conversion
    split_b3<<<768, 192, 0, stream>>>(proj_w, Bp, PC);

    // 5) feature maps
    feat_map<<<PB * PH * (PN / 32), 256, 0, stream>>>(qkv, rm, qf, kf);

    // 6) KV/s partials (8 n-chunks) -> reduce
    kv_s_kernel<<<dim3(96, 8), 256, 0, stream>>>(qkv, kf, kvp, sbufp);
    kv_reduce<<<3072, 256, 0, stream>>>(kvp, sbufp, kvf, sf);

    // 7) apply + fused denom, writes split-f16 oh
    apply_kernel<<<96 * 32, 256, 0, stream>>>(qf, kvf, sf, ohA);

    // 8) out = oh @ proj_w^T + proj_b
    gemm_mfma<<<dim3(6, 64), 256, 0, stream>>>(ohA, 1536, 1536, Bp, 2304,
                                               out, 768, 0, 2304, proj_b);
}

// Round 4
// 418.114 us; speedup vs baseline: 2.0174x; 1.0291x over previous
//
#include <hip/hip_runtime.h>
#include <hip/hip_bf16.h>

// Problem constants: B=8, N=1024, C=768, H=12, D=64, M=128
#define PB 8
#define PN 1024
#define PC 768
#define PH 12
#define PD 64
#define PM 128
#define SQ 0.35355339059327373f      // (D^-0.5)^0.5
#define MSCALE 0.08838834764831843f  // M^-0.5

typedef _Float16 f16;
typedef f16 f16x8 __attribute__((ext_vector_type(8)));
typedef f16 f16x4 __attribute__((ext_vector_type(4)));
typedef float f32x4 __attribute__((ext_vector_type(4)));

// ---------------- conversion kernels: fp32 -> split f16 ----------------
__global__ __launch_bounds__(192) void split_a2(const float* __restrict__ src,
                                                f16* __restrict__ dst, int cols) {
    const int r = blockIdx.x;
    const int c = threadIdx.x * 4;
    float4 v = *(const float4*)&src[(size_t)r * cols + c];
    f16x4 hi, lo;
    hi.x = (f16)v.x; lo.x = (f16)(v.x - (float)hi.x);
    hi.y = (f16)v.y; lo.y = (f16)(v.y - (float)hi.y);
    hi.z = (f16)v.z; lo.z = (f16)(v.z - (float)hi.z);
    hi.w = (f16)v.w; lo.w = (f16)(v.w - (float)hi.w);
    f16* d = dst + (size_t)r * 2 * cols;
    *(f16x4*)&d[c] = hi;
    *(f16x4*)&d[cols + c] = lo;
}

__global__ __launch_bounds__(192) void split_b3(const float* __restrict__ src,
                                                f16* __restrict__ dst, int cols) {
    const int r = blockIdx.x;
    const int c = threadIdx.x * 4;
    float4 v = *(const float4*)&src[(size_t)r * cols + c];
    f16x4 hi, lo;
    hi.x = (f16)v.x; lo.x = (f16)(v.x - (float)hi.x);
    hi.y = (f16)v.y; lo.y = (f16)(v.y - (float)hi.y);
    hi.z = (f16)v.z; lo.z = (f16)(v.z - (float)hi.z);
    hi.w = (f16)v.w; lo.w = (f16)(v.w - (float)hi.w);
    f16* d = dst + (size_t)r * 3 * cols;
    *(f16x4*)&d[c] = hi;
    *(f16x4*)&d[cols + c] = hi;
    *(f16x4*)&d[2 * cols + c] = lo;
}

__global__ __launch_bounds__(192) void conv_hi(const float* __restrict__ src,
                                               f16* __restrict__ dst, int cols) {
    const int r = blockIdx.x;
    const int c = threadIdx.x * 4;
    float4 v = *(const float4*)&src[(size_t)r * cols + c];
    f16x4 hi;
    hi.x = (f16)v.x; hi.y = (f16)v.y; hi.z = (f16)v.z; hi.w = (f16)v.w;
    *(f16x4*)&dst[(size_t)r * cols + c] = hi;
}

// ---------------- MFMA GEMM: C[i,j] = sum_k A[i,ka]*B[j,k] (+bias) ----------------
// 128xBN tile, BK=32, 4 waves (2x2), mfma_f32_16x16x32_f16, global_load_lds x16.
// LDS layout XOR-swizzled at 16B-chunk granularity: slot(row, p) holds logical
// chunk c = p ^ ((row>>1)&3)  -> fragment reads are 2-way-conflict (free).
// Staging composes with the wave-uniform lane->LDS mapping of global_load_lds by
// permuting the global SOURCE chunk: lane l loads chunk (l&3)^((l>>3)&3).
template<int BN>
__global__ __launch_bounds__(256) void gemm_mfma(
        const f16* __restrict__ A, int lda, int wrapA,
        const f16* __restrict__ Bm, int ldb,
        float* __restrict__ Cm, int ldc, int colOff, int Kp,
        const float* __restrict__ bias)
{
    constexpr int JT = BN / 32;          // col 16-tiles per wave
    __shared__ f16 As[128 * 32];
    __shared__ f16 Bs[BN * 32];
    const int t = threadIdx.x;
    const int wave = t >> 6, lane = t & 63;
    const int wm = wave >> 1, wn = wave & 1;
    const int bi = blockIdx.y * 128, bj = blockIdx.x * BN;

    f32x4 acc[4][JT] = {};

    const int srow16 = lane >> 2;                               // 0..15
    const int schunk = ((lane & 3) ^ ((lane >> 3) & 3)) * 8;    // swizzled source chunk
    const f16* Ap = A + (size_t)(bi + wave * 32 + srow16) * lda + schunk;
    f16* AsB = &As[wave * 32 * 32];
    const int brow0 = (BN == 128) ? wave * 32 : wave * 16;
    const f16* Bp = Bm + (size_t)(bj + brow0 + srow16) * ldb + schunk;
    f16* BsB = &Bs[brow0 * 32];

    const int nK = Kp / 32;
    for (int kt = 0; kt < nK; ++kt) {
        const int k0 = kt * 32;
        const int ka = (k0 >= wrapA) ? k0 - wrapA : k0;
        __syncthreads();
        __builtin_amdgcn_global_load_lds(
            (const __attribute__((address_space(1))) void*)(Ap + ka),
            (__attribute__((address_space(3))) void*)(AsB), 16, 0, 0);
        __builtin_amdgcn_global_load_lds(
            (const __attribute__((address_space(1))) void*)(Ap + ka + (size_t)16 * lda),
            (__attribute__((address_space(3))) void*)(AsB + 16 * 32), 16, 0, 0);
        __builtin_amdgcn_global_load_lds(
            (const __attribute__((address_space(1))) void*)(Bp + k0),
            (__attribute__((address_space(3))) void*)(BsB), 16, 0, 0);
        if (BN == 128)
            __builtin_amdgcn_global_load_lds(
                (const __attribute__((address_space(1))) void*)(Bp + k0 + (size_t)16 * ldb),
                (__attribute__((address_space(3))) void*)(BsB + 16 * 32), 16, 0, 0);
        __syncthreads();

        f16x8 af[4], bf[JT];
        #pragma unroll
        for (int i = 0; i < 4; ++i) {
            const int r = wm * 64 + i * 16 + (lane & 15);
            const int p = (lane >> 4) ^ ((r >> 1) & 3);
            af[i] = *(const f16x8*)&As[r * 32 + p * 8];
        }
        #pragma unroll
        for (int j = 0; j < JT; ++j) {
            const int r = wn * (BN / 2) + j * 16 + (lane & 15);
            const int p = (lane >> 4) ^ ((r >> 1) & 3);
            bf[j] = *(const f16x8*)&Bs[r * 32 + p * 8];
        }
        #pragma unroll
        for (int i = 0; i < 4; ++i)
            #pragma unroll
            for (int j = 0; j < JT; ++j)
                acc[i][j] = __builtin_amdgcn_mfma_f32_16x16x32_f16(af[i], bf[j], acc[i][j], 0, 0, 0);
    }

    const int cr = (lane >> 4) * 4, cc = lane & 15;
    #pragma unroll
    for (int i = 0; i < 4; ++i) {
        const int row = bi + wm * 64 + i * 16 + cr;
        #pragma unroll
        for (int j = 0; j < JT; ++j) {
            const int col = bj + wn * (BN / 2) + j * 16 + cc;
            const float bv = bias ? bias[col] : 0.f;
            #pragma unroll
            for (int r = 0; r < 4; ++r)
                Cm[(size_t)(row + r) * ldc + colOff + col] = acc[i][j][r] + bv;
        }
    }
}

// ---------------- Feature map: qf/kf = exp(z@R[h] - 0.5|z|^2) * M^-0.5, f16 out ----------------
__global__ __launch_bounds__(256) void feat_map(
        const float* __restrict__ qkv, const float* __restrict__ rm,
        f16* __restrict__ qf, f16* __restrict__ kf)
{
    __shared__ float zs[2][32][64];
    __shared__ float sqn[2][32];
    const int t = threadIdx.x;
    int bx = blockIdx.x;
    const int chunk = bx & 31; bx >>= 5;
    const int h = bx % PH, b = bx / PH;
    const int n0 = chunk * 32;
    const int m = t & 127, wh = t >> 7;

    float Rr[64];
    const float* rh = rm + (size_t)h * PD * PM + m;
    #pragma unroll
    for (int d = 0; d < 64; ++d) Rr[d] = rh[d * PM];

    const float* qb = qkv + (size_t)(b * PN + n0) * (3 * PC) + h * PD;
    #pragma unroll
    for (int i = 0; i < 16; ++i) {
        int idx = i * 256 + t;
        int w = idx >> 11, row = (idx >> 6) & 31, d = idx & 63;
        zs[w][row][d] = qb[(size_t)row * (3 * PC) + w * PC + d] * SQ;
    }
    __syncthreads();
    if (t < 64) {
        int w = t >> 5, row = t & 31;
        float s2 = 0.f;
        #pragma unroll
        for (int d = 0; d < 64; ++d) { float z = zs[w][row][d]; s2 += z * z; }
        sqn[w][row] = 0.5f * s2;
    }
    __syncthreads();

    f16* op = (wh ? kf : qf) + ((size_t)((b * PH + h) * PN + n0)) * PM + m;
    for (int r = 0; r < 32; ++r) {
        float logit = 0.f;
        #pragma unroll
        for (int d4 = 0; d4 < 16; ++d4) {
            float4 z = *(const float4*)&zs[wh][r][d4 * 4];
            logit += z.x * Rr[4 * d4] + z.y * Rr[4 * d4 + 1]
                   + z.z * Rr[4 * d4 + 2] + z.w * Rr[4 * d4 + 3];
        }
        op[(size_t)r * PM] = (f16)(__expf(logit - sqn[wh][r]) * MSCALE);
    }
}

// ---------------- KV partials over 8 n-chunks, s partials ----------------
__global__ __launch_bounds__(256) void kv_s_kernel(
        const float* __restrict__ qkv, const f16* __restrict__ kf,
        float* __restrict__ kvp, float* __restrict__ sbufp)
{
    __shared__ float vs[128][64];
    const int t = threadIdx.x;
    const int bh = blockIdx.x;
    const int nc = blockIdx.y;
    const int n0 = nc * 128;
    const int b = bh / PH, h = bh % PH;
    const int m = t & 127, dh = t >> 7;

    const float* vb = qkv + (size_t)b * PN * (3 * PC) + 2 * PC + h * PD;
    #pragma unroll
    for (int i = 0; i < 32; ++i) {
        int idx = i * 256 + t;
        int row = idx >> 6, d = idx & 63;
        vs[row][d] = vb[(size_t)(n0 + row) * (3 * PC) + d];
    }
    __syncthreads();

    float acc[32];
    #pragma unroll
    for (int j = 0; j < 32; ++j) acc[j] = 0.f;
    float sacc = 0.f;
    const f16* kfb = kf + ((size_t)bh * PN + n0) * PM + m;
    #pragma unroll 8
    for (int nn = 0; nn < 128; ++nn) {
        float kq = (float)kfb[(size_t)nn * PM];
        sacc += kq;
        #pragma unroll
        for (int j = 0; j < 32; ++j)
            acc[j] += kq * vs[nn][dh * 32 + j];
    }

    float* kvo = kvp + (((size_t)(nc * 96 + bh) * PM + m)) * PD + dh * 32;
    #pragma unroll
    for (int j = 0; j < 32; ++j) kvo[j] = acc[j];
    if (dh == 0)
        sbufp[(size_t)(nc * 96 + bh) * PM + m] = sacc;
}

// ---------------- reduce 8 kv/s partials ----------------
__global__ __launch_bounds__(256) void kv_reduce(
        const float* __restrict__ kvp, const float* __restrict__ sbufp,
        float* __restrict__ kv, float* __restrict__ s)
{
    const int idx = blockIdx.x * 256 + threadIdx.x;  // 0..786431
    float a = 0.f;
    #pragma unroll
    for (int c = 0; c < 8; ++c) a += kvp[(size_t)c * 786432 + idx];
    kv[idx] = a;
    if (idx < 96 * PM) {
        float sa = 0.f;
        #pragma unroll
        for (int c = 0; c < 8; ++c) sa += sbufp[(size_t)c * 96 * PM + idx];
        s[idx] = sa;
    }
}

// ---------------- apply: oh = (qf @ KV) / (qf . s), split-f16 out ----------------
__global__ __launch_bounds__(256) void apply_kernel(
        const f16* __restrict__ qf, const float* __restrict__ kv,
        const float* __restrict__ sv, f16* __restrict__ ohA)
{
    __shared__ float kvs[128][64];
    __shared__ float qfs[32][128];
    __shared__ float ss[128];
    __shared__ float part[32][8];
    __shared__ float dns[32];
    const int t = threadIdx.x;
    const int bh = blockIdx.x >> 5;
    const int n0 = (blockIdx.x & 31) * 32;
    const int b = bh / PH, h = bh % PH;

    const float* kv0 = kv + (size_t)bh * PM * PD;
    #pragma unroll
    for (int i = 0; i < 32; ++i) {
        int idx = i * 256 + t;
        kvs[idx >> 6][idx & 63] = kv0[idx];
    }
    const f16* qfb = qf + ((size_t)bh * PN + n0) * PM;
    #pragma unroll
    for (int i = 0; i < 16; ++i) {
        int idx = i * 256 + t;
        qfs[idx >> 7][idx & 127] = (float)qfb[idx];
    }
    if (t < 128) ss[t] = sv[(size_t)bh * PM + t];
    __syncthreads();
    {
        const int row = t & 31, seg = t >> 5;
        float p = 0.f;
        #pragma unroll
        for (int mm = seg * 16; mm < seg * 16 + 16; ++mm)
            p += qfs[row][mm] * ss[mm];
        part[row][seg] = p;
    }
    __syncthreads();
    if (t < 32) {
        float dsum = 0.f;
        #pragma unroll
        for (int j = 0; j < 8; ++j) dsum += part[t][j];
        dns[t] = (dsum < 1e-12f) ? 1e-12f : dsum;
    }
    __syncthreads();

    const int d = t & 63, rg = t >> 6;
    float acc[8] = {0.f};
    for (int mm = 0; mm < 128; ++mm) {
        float kvv = kvs[mm][d];
        #pragma unroll
        for (int j = 0; j < 8; ++j)
            acc[j] += qfs[rg * 8 + j][mm] * kvv;
    }
    f16* ob = ohA + (size_t)(b * PN + n0) * 1536 + h * PD + d;
    #pragma unroll
    for (int j = 0; j < 8; ++j) {
        const int r = rg * 8 + j;
        float v = acc[j] / dns[r];
        f16 hi = (f16)v;
        f16 lo = (f16)(v - (float)hi);
        ob[(size_t)r * 1536] = hi;
        ob[(size_t)r * 1536 + PC] = lo;
    }
}

extern "C" void kernel_launch(void* const* d_in, const int* in_sizes, int n_in,
                              void* d_out, int out_size, void* d_ws, size_t ws_size,
                              hipStream_t stream) {
    const float* x      = (const float*)d_in[0];  // [B,N,C]
    const float* qkv_w  = (const float*)d_in[1];  // [3C,C]
    const float* proj_w = (const float*)d_in[2];  // [C,C]
    const float* proj_b = (const float*)d_in[3];  // [C]
    const float* rm     = (const float*)d_in[4];  // [H,D,M]
    float* out = (float*)d_out;                    // [B,N,C] = 25,165,824 B

    char* ws = (char*)d_ws;
    // disjoint regions (total ~191.5 MB)
    float* qkv = (float*)(ws);                          // [8192][2304] f32   = 75,497,472
    f16*   qf  = (f16*)(ws + 75497472);                 // [96][1024][128]    = 25,165,824
    f16*   kf  = (f16*)(ws + 100663296);                // [96][1024][128]    = 25,165,824
    f16*   Asp = (f16*)(ws + 125829120);                // [8192][1536]       = 25,165,824
    f16*   Bqk = (f16*)(ws + 150994944);                // [1536][2304]       =  7,077,888
    f16*   Bv  = (f16*)(ws + 158072832);                // [768][768]         =  1,179,648
    f16*   Bp  = (f16*)(ws + 159252480);                // [768][2304]        =  3,538,944
    float* sbufp = (float*)(ws + 162791424);            // [8][96][128] f32   =    393,216
    float* kvf   = (float*)(ws + 163184640);            // [96][128][64] f32  =  3,145,728
    float* sf    = (float*)(ws + 166330368);            // [96][128] f32      =     49,152
    f16*   ohA   = (f16*)(ws + 166379520);              // [8192][1536]       = 25,165,824
    // kv partials live in d_out (dead until final gemm): [8][96][128][64] f32 = 25,165,824
    float* kvp = (float*)d_out;

    // 1) conversions
    split_a2<<<8192, 192, 0, stream>>>(x, Asp, PC);
    split_b3<<<1536, 192, 0, stream>>>(qkv_w, Bqk, PC);
    conv_hi <<<768, 192, 0, stream>>>(qkv_w + (size_t)1536 * PC, Bv, PC);
    split_b3<<<768, 192, 0, stream>>>(proj_w, Bp, PC);

    // 2) q,k projection: [8192][1536] = Asp(wrap 1536) x Bqk, K'=2304
    gemm_mfma<128><<<dim3(12, 64), 256, 0, stream>>>(Asp, 1536, 1536, Bqk, 2304,
                                                     qkv, 2304, 0, 2304, nullptr);
    // 3) v projection: plain f16, K=768, BN=64 tiles for occupancy
    gemm_mfma<64><<<dim3(12, 64), 256, 0, stream>>>(Asp, 1536, 1 << 30, Bv, 768,
                                                    qkv, 2304, 1536, 768, nullptr);

    // 4) feature maps (f16 out)
    feat_map<<<PB * PH * (PN / 32), 256, 0, stream>>>(qkv, rm, qf, kf);

    // 5) KV/s partials (8 n-chunks) -> reduce
    kv_s_kernel<<<dim3(96, 8), 256, 0, stream>>>(qkv, kf, kvp, sbufp);
    kv_reduce<<<3072, 256, 0, stream>>>(kvp, sbufp, kvf, sf);

    // 6) apply + fused denom, writes split-f16 oh
    apply_kernel<<<96 * 32, 256, 0, stream>>>(qf, kvf, sf, ohA);

    // 7) out = oh @ proj_w^T + proj_b, BN=64 tiles
    gemm_mfma<64><<<dim3(12, 64), 256, 0, stream>>>(ohA, 1536, 1536, Bp, 2304,
                                                    out, 768, 0, 2304, proj_b);
}

// Round 5
// 327.553 us; speedup vs baseline: 2.5752x; 1.2765x over previous
//
#include <hip/hip_runtime.h>
#include <hip/hip_bf16.h>

// Problem constants: B=8, N=1024, C=768, H=12, D=64, M=128
#define PB 8
#define PN 1024
#define PC 768
#define PH 12
#define PD 64
#define PM 128
#define SQ 0.35355339059327373f      // (D^-0.5)^0.5
#define MSCALE 0.08838834764831843f  // M^-0.5

typedef _Float16 f16;
typedef f16 f16x8 __attribute__((ext_vector_type(8)));
typedef f16 f16x4 __attribute__((ext_vector_type(4)));
typedef float f32x4 __attribute__((ext_vector_type(4)));

// ---------------- conversion: fp32 -> f16 (row-wise, 4 elems/thread) ----------------
__global__ __launch_bounds__(192) void conv_hi(const float* __restrict__ src,
                                               f16* __restrict__ dst, int cols) {
    const int r = blockIdx.x;
    const int c = threadIdx.x * 4;
    float4 v = *(const float4*)&src[(size_t)r * cols + c];
    f16x4 hi;
    hi.x = (f16)v.x; hi.y = (f16)v.y; hi.z = (f16)v.z; hi.w = (f16)v.w;
    *(f16x4*)&dst[(size_t)r * cols + c] = hi;
}

// ---------------- MFMA GEMM: C[i,j] = sum_k A[i,k]*B[j,k] (+bias) ----------------
// 128xBN tile, BK=32, 4 waves (2x2), mfma_f32_16x16x32_f16, global_load_lds x16.
// LDS XOR-swizzled at 16B-chunk granularity (verified conflict-free in r4).
template<int BN>
__global__ __launch_bounds__(256) void gemm_mfma(
        const f16* __restrict__ A, int lda,
        const f16* __restrict__ Bm, int ldb,
        float* __restrict__ Cm, int ldc, int colOff, int Kp,
        const float* __restrict__ bias)
{
    constexpr int JT = BN / 32;          // col 16-tiles per wave
    __shared__ f16 As[128 * 32];
    __shared__ f16 Bs[BN * 32];
    const int t = threadIdx.x;
    const int wave = t >> 6, lane = t & 63;
    const int wm = wave >> 1, wn = wave & 1;
    const int bi = blockIdx.y * 128, bj = blockIdx.x * BN;

    f32x4 acc[4][JT] = {};

    const int srow16 = lane >> 2;                               // 0..15
    const int schunk = ((lane & 3) ^ ((lane >> 3) & 3)) * 8;    // swizzled source chunk
    const f16* Ap = A + (size_t)(bi + wave * 32 + srow16) * lda + schunk;
    f16* AsB = &As[wave * 32 * 32];
    const int brow0 = (BN == 128) ? wave * 32 : wave * 16;
    const f16* Bp = Bm + (size_t)(bj + brow0 + srow16) * ldb + schunk;
    f16* BsB = &Bs[brow0 * 32];

    const int nK = Kp / 32;
    for (int kt = 0; kt < nK; ++kt) {
        const int k0 = kt * 32;
        __syncthreads();
        __builtin_amdgcn_global_load_lds(
            (const __attribute__((address_space(1))) void*)(Ap + k0),
            (__attribute__((address_space(3))) void*)(AsB), 16, 0, 0);
        __builtin_amdgcn_global_load_lds(
            (const __attribute__((address_space(1))) void*)(Ap + k0 + (size_t)16 * lda),
            (__attribute__((address_space(3))) void*)(AsB + 16 * 32), 16, 0, 0);
        __builtin_amdgcn_global_load_lds(
            (const __attribute__((address_space(1))) void*)(Bp + k0),
            (__attribute__((address_space(3))) void*)(BsB), 16, 0, 0);
        if (BN == 128)
            __builtin_amdgcn_global_load_lds(
                (const __attribute__((address_space(1))) void*)(Bp + k0 + (size_t)16 * ldb),
                (__attribute__((address_space(3))) void*)(BsB + 16 * 32), 16, 0, 0);
        __syncthreads();

        f16x8 af[4], bf[JT];
        #pragma unroll
        for (int i = 0; i < 4; ++i) {
            const int r = wm * 64 + i * 16 + (lane & 15);
            const int p = (lane >> 4) ^ ((r >> 1) & 3);
            af[i] = *(const f16x8*)&As[r * 32 + p * 8];
        }
        #pragma unroll
        for (int j = 0; j < JT; ++j) {
            const int r = wn * (BN / 2) + j * 16 + (lane & 15);
            const int p = (lane >> 4) ^ ((r >> 1) & 3);
            bf[j] = *(const f16x8*)&Bs[r * 32 + p * 8];
        }
        #pragma unroll
        for (int i = 0; i < 4; ++i)
            #pragma unroll
            for (int j = 0; j < JT; ++j)
                acc[i][j] = __builtin_amdgcn_mfma_f32_16x16x32_f16(af[i], bf[j], acc[i][j], 0, 0, 0);
    }

    const int cr = (lane >> 4) * 4, cc = lane & 15;
    #pragma unroll
    for (int i = 0; i < 4; ++i) {
        const int row = bi + wm * 64 + i * 16 + cr;
        #pragma unroll
        for (int j = 0; j < JT; ++j) {
            const int col = bj + wn * (BN / 2) + j * 16 + cc;
            const float bv = bias ? bias[col] : 0.f;
            #pragma unroll
            for (int r = 0; r < 4; ++r)
                Cm[(size_t)(row + r) * ldc + colOff + col] = acc[i][j][r] + bv;
        }
    }
}

// ---------------- Feature map: qf/kf = exp(z@R[h] - 0.5|z|^2) * M^-0.5, f16 out ----------------
__global__ __launch_bounds__(256) void feat_map(
        const float* __restrict__ qkv, const float* __restrict__ rm,
        f16* __restrict__ qf, f16* __restrict__ kf)
{
    __shared__ float zs[2][32][64];
    __shared__ float sqn[2][32];
    const int t = threadIdx.x;
    int bx = blockIdx.x;
    const int chunk = bx & 31; bx >>= 5;
    const int h = bx % PH, b = bx / PH;
    const int n0 = chunk * 32;
    const int m = t & 127, wh = t >> 7;

    float Rr[64];
    const float* rh = rm + (size_t)h * PD * PM + m;
    #pragma unroll
    for (int d = 0; d < 64; ++d) Rr[d] = rh[d * PM];

    const float* qb = qkv + (size_t)(b * PN + n0) * (3 * PC) + h * PD;
    #pragma unroll
    for (int i = 0; i < 16; ++i) {
        int idx = i * 256 + t;
        int w = idx >> 11, row = (idx >> 6) & 31, d = idx & 63;
        zs[w][row][d] = qb[(size_t)row * (3 * PC) + w * PC + d] * SQ;
    }
    __syncthreads();
    if (t < 64) {
        int w = t >> 5, row = t & 31;
        float s2 = 0.f;
        #pragma unroll
        for (int d = 0; d < 64; ++d) { float z = zs[w][row][d]; s2 += z * z; }
        sqn[w][row] = 0.5f * s2;
    }
    __syncthreads();

    f16* op = (wh ? kf : qf) + ((size_t)((b * PH + h) * PN + n0)) * PM + m;
    for (int r = 0; r < 32; ++r) {
        float logit = 0.f;
        #pragma unroll
        for (int d4 = 0; d4 < 16; ++d4) {
            float4 z = *(const float4*)&zs[wh][r][d4 * 4];
            logit += z.x * Rr[4 * d4] + z.y * Rr[4 * d4 + 1]
                   + z.z * Rr[4 * d4 + 2] + z.w * Rr[4 * d4 + 3];
        }
        op[(size_t)r * PM] = (f16)(__expf(logit - sqn[wh][r]) * MSCALE);
    }
}

// ---------------- KV partials over 8 n-chunks, s partials ----------------
__global__ __launch_bounds__(256) void kv_s_kernel(
        const float* __restrict__ qkv, const f16* __restrict__ kf,
        float* __restrict__ kvp, float* __restrict__ sbufp)
{
    __shared__ float vs[128][64];
    const int t = threadIdx.x;
    const int bh = blockIdx.x;
    const int nc = blockIdx.y;
    const int n0 = nc * 128;
    const int b = bh / PH, h = bh % PH;
    const int m = t & 127, dh = t >> 7;

    const float* vb = qkv + (size_t)b * PN * (3 * PC) + 2 * PC + h * PD;
    #pragma unroll
    for (int i = 0; i < 32; ++i) {
        int idx = i * 256 + t;
        int row = idx >> 6, d = idx & 63;
        vs[row][d] = vb[(size_t)(n0 + row) * (3 * PC) + d];
    }
    __syncthreads();

    float acc[32];
    #pragma unroll
    for (int j = 0; j < 32; ++j) acc[j] = 0.f;
    float sacc = 0.f;
    const f16* kfb = kf + ((size_t)bh * PN + n0) * PM + m;
    #pragma unroll 8
    for (int nn = 0; nn < 128; ++nn) {
        float kq = (float)kfb[(size_t)nn * PM];
        sacc += kq;
        #pragma unroll
        for (int j = 0; j < 32; ++j)
            acc[j] += kq * vs[nn][dh * 32 + j];
    }

    float* kvo = kvp + (((size_t)(nc * 96 + bh) * PM + m)) * PD + dh * 32;
    #pragma unroll
    for (int j = 0; j < 32; ++j) kvo[j] = acc[j];
    if (dh == 0)
        sbufp[(size_t)(nc * 96 + bh) * PM + m] = sacc;
}

// ---------------- reduce 8 kv/s partials ----------------
__global__ __launch_bounds__(256) void kv_reduce(
        const float* __restrict__ kvp, const float* __restrict__ sbufp,
        float* __restrict__ kv, float* __restrict__ s)
{
    const int idx = blockIdx.x * 256 + threadIdx.x;  // 0..786431
    float a = 0.f;
    #pragma unroll
    for (int c = 0; c < 8; ++c) a += kvp[(size_t)c * 786432 + idx];
    kv[idx] = a;
    if (idx < 96 * PM) {
        float sa = 0.f;
        #pragma unroll
        for (int c = 0; c < 8; ++c) sa += sbufp[(size_t)c * 96 * PM + idx];
        s[idx] = sa;
    }
}

// ---------------- apply: oh = (qf @ KV) / (qf . s), plain f16 out [B,N,C] ----------------
__global__ __launch_bounds__(256) void apply_kernel(
        const f16* __restrict__ qf, const float* __restrict__ kv,
        const float* __restrict__ sv, f16* __restrict__ ohA)
{
    __shared__ float kvs[128][64];
    __shared__ float qfs[32][128];
    __shared__ float ss[128];
    __shared__ float part[32][8];
    __shared__ float dns[32];
    const int t = threadIdx.x;
    const int bh = blockIdx.x >> 5;
    const int n0 = (blockIdx.x & 31) * 32;
    const int b = bh / PH, h = bh % PH;

    const float* kv0 = kv + (size_t)bh * PM * PD;
    #pragma unroll
    for (int i = 0; i < 32; ++i) {
        int idx = i * 256 + t;
        kvs[idx >> 6][idx & 63] = kv0[idx];
    }
    const f16* qfb = qf + ((size_t)bh * PN + n0) * PM;
    #pragma unroll
    for (int i = 0; i < 16; ++i) {
        int idx = i * 256 + t;
        qfs[idx >> 7][idx & 127] = (float)qfb[idx];
    }
    if (t < 128) ss[t] = sv[(size_t)bh * PM + t];
    __syncthreads();
    {
        const int row = t & 31, seg = t >> 5;
        float p = 0.f;
        #pragma unroll
        for (int mm = seg * 16; mm < seg * 16 + 16; ++mm)
            p += qfs[row][mm] * ss[mm];
        part[row][seg] = p;
    }
    __syncthreads();
    if (t < 32) {
        float dsum = 0.f;
        #pragma unroll
        for (int j = 0; j < 8; ++j) dsum += part[t][j];
        dns[t] = (dsum < 1e-12f) ? 1e-12f : dsum;
    }
    __syncthreads();

    const int d = t & 63, rg = t >> 6;
    float acc[8] = {0.f};
    for (int mm = 0; mm < 128; ++mm) {
        float kvv = kvs[mm][d];
        #pragma unroll
        for (int j = 0; j < 8; ++j)
            acc[j] += qfs[rg * 8 + j][mm] * kvv;
    }
    f16* ob = ohA + (size_t)(b * PN + n0) * PC + h * PD + d;
    #pragma unroll
    for (int j = 0; j < 8; ++j) {
        const int r = rg * 8 + j;
        ob[(size_t)r * PC] = (f16)(acc[j] / dns[r]);
    }
}

extern "C" void kernel_launch(void* const* d_in, const int* in_sizes, int n_in,
                              void* d_out, int out_size, void* d_ws, size_t ws_size,
                              hipStream_t stream) {
    const float* x      = (const float*)d_in[0];  // [B,N,C]
    const float* qkv_w  = (const float*)d_in[1];  // [3C,C]
    const float* proj_w = (const float*)d_in[2];  // [C,C]
    const float* proj_b = (const float*)d_in[3];  // [C]
    const float* rm     = (const float*)d_in[4];  // [H,D,M]
    float* out = (float*)d_out;                    // [B,N,C] = 25,165,824 B

    char* ws = (char*)d_ws;
    // disjoint regions (total ~160 MB)
    float* qkv = (float*)(ws);                          // [8192][2304] f32   = 75,497,472
    f16*   qf  = (f16*)(ws + 75497472);                 // [96][1024][128]    = 25,165,824
    f16*   kf  = (f16*)(ws + 100663296);                // [96][1024][128]    = 25,165,824
    f16*   Ax  = (f16*)(ws + 125829120);                // [8192][768]        = 12,582,912
    f16*   Bqk = (f16*)(ws + 138412032);                // [2304][768]        =  3,538,944
    f16*   Bp  = (f16*)(ws + 141950976);                // [768][768]         =  1,179,648
    float* sbufp = (float*)(ws + 143130624);            // [8][96][128] f32   =    393,216
    float* kvf   = (float*)(ws + 143523840);            // [96][128][64] f32  =  3,145,728
    float* sf    = (float*)(ws + 146669568);            // [96][128] f32      =     49,152
    f16*   ohA   = (f16*)(ws + 146718720);              // [8192][768]        = 12,582,912
    // kv partials live in d_out (dead until final gemm): [8][96][128][64] f32
    float* kvp = (float*)d_out;

    // 1) conversions to f16
    conv_hi<<<8192, 192, 0, stream>>>(x, Ax, PC);
    conv_hi<<<2304, 192, 0, stream>>>(qkv_w, Bqk, PC);
    conv_hi<<<768, 192, 0, stream>>>(proj_w, Bp, PC);

    // 2) fused q,k,v projection: [8192][2304] = Ax x Bqk, K=768
    gemm_mfma<128><<<dim3(18, 64), 256, 0, stream>>>(Ax, PC, Bqk, PC,
                                                     qkv, 2304, 0, PC, nullptr);

    // 3) feature maps (f16 out)
    feat_map<<<PB * PH * (PN / 32), 256, 0, stream>>>(qkv, rm, qf, kf);

    // 4) KV/s partials (8 n-chunks) -> reduce
    kv_s_kernel<<<dim3(96, 8), 256, 0, stream>>>(qkv, kf, kvp, sbufp);
    kv_reduce<<<3072, 256, 0, stream>>>(kvp, sbufp, kvf, sf);

    // 5) apply + fused denom, writes plain f16 oh [B,N,C]
    apply_kernel<<<96 * 32, 256, 0, stream>>>(qf, kvf, sf, ohA);

    // 6) out = oh @ proj_w^T + proj_b, BN=64 tiles, K=768
    gemm_mfma<64><<<dim3(12, 64), 256, 0, stream>>>(ohA, PC, Bp, PC,
                                                    out, PC, 0, PC, proj_b);
}

// Round 6
// 283.087 us; speedup vs baseline: 2.9797x; 1.1571x over previous
//
#include <hip/hip_runtime.h>
#include <hip/hip_bf16.h>

// Problem constants: B=8, N=1024, C=768, H=12, D=64, M=128
#define PB 8
#define PN 1024
#define PC 768
#define PH 12
#define PD 64
#define PM 128
#define SQ 0.35355339059327373f      // (D^-0.5)^0.5 = D^-0.25
#define MSCALE 0.08838834764831843f  // M^-0.5

typedef _Float16 f16;
typedef f16 f16x8 __attribute__((ext_vector_type(8)));
typedef f16 f16x4 __attribute__((ext_vector_type(4)));
typedef float f32x4 __attribute__((ext_vector_type(4)));

// ---------------- conversion: fp32 -> f16 (row-wise, 4 elems/thread) ----------------
__global__ __launch_bounds__(192) void conv_hi(const float* __restrict__ src,
                                               f16* __restrict__ dst, int cols) {
    const int r = blockIdx.x;
    const int c = threadIdx.x * 4;
    float4 v = *(const float4*)&src[(size_t)r * cols + c];
    f16x4 hi;
    hi.x = (f16)v.x; hi.y = (f16)v.y; hi.z = (f16)v.z; hi.w = (f16)v.w;
    *(f16x4*)&dst[(size_t)r * cols + c] = hi;
}

// Rt[h][m][d] = (f16) rm[h][d][m]  (transpose per head)
__global__ __launch_bounds__(256) void conv_rt(const float* __restrict__ rm,
                                               f16* __restrict__ Rt) {
    const int h = blockIdx.x;
    for (int e = threadIdx.x; e < PD * PM; e += 256) {
        int m = e >> 6, d = e & 63;
        Rt[(size_t)h * PD * PM + e] = (f16)rm[(size_t)h * PD * PM + d * PM + m];
    }
}

// ---------------- fused qkv GEMM: emits z_q, z_k (f16, scaled), v (f16), sqnorms ----------------
// 128x128 tile, BK=32, 4 waves (2x2), swizzled LDS (verified conflict-free r4).
__global__ __launch_bounds__(256) void gemm_qkv(
        const f16* __restrict__ A,    // [8192][768] x in f16
        const f16* __restrict__ Bm,   // [2304][768] qkv_w in f16
        f16* __restrict__ zq, f16* __restrict__ zk, f16* __restrict__ vh,
        float* __restrict__ sqq, float* __restrict__ sqk)
{
    __shared__ f16 As[128 * 32];
    __shared__ f16 Bs[128 * 32];
    const int t = threadIdx.x;
    const int wave = t >> 6, lane = t & 63;
    const int wm = wave >> 1, wn = wave & 1;
    const int bi = blockIdx.y * 128, bj = blockIdx.x * 128;

    f32x4 acc[4][4] = {};

    const int srow16 = lane >> 2;
    const int schunk = ((lane & 3) ^ ((lane >> 3) & 3)) * 8;
    const f16* Ap = A + (size_t)(bi + wave * 32 + srow16) * PC + schunk;
    f16* AsB = &As[wave * 32 * 32];
    const f16* Bp = Bm + (size_t)(bj + wave * 32 + srow16) * PC + schunk;
    f16* BsB = &Bs[wave * 32 * 32];

    for (int kt = 0; kt < 24; ++kt) {
        const int k0 = kt * 32;
        __syncthreads();
        __builtin_amdgcn_global_load_lds(
            (const __attribute__((address_space(1))) void*)(Ap + k0),
            (__attribute__((address_space(3))) void*)(AsB), 16, 0, 0);
        __builtin_amdgcn_global_load_lds(
            (const __attribute__((address_space(1))) void*)(Ap + k0 + (size_t)16 * PC),
            (__attribute__((address_space(3))) void*)(AsB + 16 * 32), 16, 0, 0);
        __builtin_amdgcn_global_load_lds(
            (const __attribute__((address_space(1))) void*)(Bp + k0),
            (__attribute__((address_space(3))) void*)(BsB), 16, 0, 0);
        __builtin_amdgcn_global_load_lds(
            (const __attribute__((address_space(1))) void*)(Bp + k0 + (size_t)16 * PC),
            (__attribute__((address_space(3))) void*)(BsB + 16 * 32), 16, 0, 0);
        __syncthreads();

        f16x8 af[4], bf[4];
        #pragma unroll
        for (int i = 0; i < 4; ++i) {
            const int r = wm * 64 + i * 16 + (lane & 15);
            const int p = (lane >> 4) ^ ((r >> 1) & 3);
            af[i] = *(const f16x8*)&As[r * 32 + p * 8];
        }
        #pragma unroll
        for (int j = 0; j < 4; ++j) {
            const int r = wn * 64 + j * 16 + (lane & 15);
            const int p = (lane >> 4) ^ ((r >> 1) & 3);
            bf[j] = *(const f16x8*)&Bs[r * 32 + p * 8];
        }
        #pragma unroll
        for (int i = 0; i < 4; ++i)
            #pragma unroll
            for (int j = 0; j < 4; ++j)
                acc[i][j] = __builtin_amdgcn_mfma_f32_16x16x32_f16(af[i], bf[j], acc[i][j], 0, 0, 0);
    }

    // epilogue: colbase selects q / k / v region (wave-uniform)
    const int quad = lane >> 4, cc = lane & 15;
    const int colbase = bj + wn * 64;           // multiple of 64
    const int b = bi >> 10;                     // block never straddles a batch
    if (colbase < 1536) {
        const int which = colbase >= 768;
        const int h = (colbase - which * 768) >> 6;
        f16* zdst = which ? zk : zq;
        float* sdst = which ? sqk : sqq;
        const size_t bh = (size_t)(b * PH + h);
        #pragma unroll
        for (int i = 0; i < 4; ++i) {
            const int row0 = bi + wm * 64 + i * 16 + quad * 4;
            #pragma unroll
            for (int r = 0; r < 4; ++r) {
                const int n = (row0 + r) & 1023;
                f16 zh[4]; float psq = 0.f;
                #pragma unroll
                for (int j = 0; j < 4; ++j) {
                    zh[j] = (f16)(acc[i][j][r] * SQ);
                    float zf = (float)zh[j];
                    psq += zf * zf;
                }
                // sum over the 16 lanes holding this head's 64 cols (same rows)
                psq += __shfl_xor(psq, 1, 64);
                psq += __shfl_xor(psq, 2, 64);
                psq += __shfl_xor(psq, 4, 64);
                psq += __shfl_xor(psq, 8, 64);
                if (cc == 0) sdst[(bh << 10) + n] = 0.5f * psq;
                f16* zp = zdst + (((bh << 10) + n) << 6);
                #pragma unroll
                for (int j = 0; j < 4; ++j) zp[j * 16 + cc] = zh[j];
            }
        }
    } else {
        const int h = (colbase - 1536) >> 6;
        const size_t bh = (size_t)(b * PH + h);
        #pragma unroll
        for (int i = 0; i < 4; ++i) {
            const int row0 = bi + wm * 64 + i * 16 + quad * 4;
            #pragma unroll
            for (int r = 0; r < 4; ++r) {
                const int n = (row0 + r) & 1023;
                f16* vp = vh + (((bh << 10) + n) << 6);
                #pragma unroll
                for (int j = 0; j < 4; ++j) vp[j * 16 + cc] = (f16)acc[i][j][r];
            }
        }
    }
}

// ---------------- feature map GEMM: qf/kf = exp(z@Rt^T - sqn) * M^-0.5 ----------------
// grid (n-tile 8, bh 96, which 2); 128x128 tile, K=64 (2 BK=32 iters).
__global__ __launch_bounds__(256) void feat_gemm(
        const f16* __restrict__ zq, const f16* __restrict__ zk,
        const f16* __restrict__ Rt,
        const float* __restrict__ sqq, const float* __restrict__ sqk,
        f16* __restrict__ qf, f16* __restrict__ kf)
{
    __shared__ f16 As[128 * 32];
    __shared__ f16 Bs[128 * 32];
    __shared__ float sqs[128];
    const int t = threadIdx.x;
    const int wave = t >> 6, lane = t & 63;
    const int wm = wave >> 1, wn = wave & 1;
    const int nt = blockIdx.x, bh = blockIdx.y, which = blockIdx.z;

    const f16* A = (which ? zk : zq) + (((size_t)bh << 10) + nt * 128) * 64;
    const f16* Bm = Rt + (size_t)(bh % PH) * (PM * PD);
    const float* sq = (which ? sqk : sqq) + (bh << 10) + nt * 128;
    f16* op = (which ? kf : qf) + (((size_t)bh << 10) + nt * 128) * PM;

    f32x4 acc[4][4] = {};
    const int srow16 = lane >> 2;
    const int schunk = ((lane & 3) ^ ((lane >> 3) & 3)) * 8;
    const f16* Ap = A + (size_t)(wave * 32 + srow16) * 64 + schunk;
    f16* AsB = &As[wave * 32 * 32];
    const f16* Bp = Bm + (size_t)(wave * 32 + srow16) * 64 + schunk;
    f16* BsB = &Bs[wave * 32 * 32];

    if (t < 128) sqs[t] = sq[t];

    #pragma unroll
    for (int kt = 0; kt < 2; ++kt) {
        const int k0 = kt * 32;
        __syncthreads();
        __builtin_amdgcn_global_load_lds(
            (const __attribute__((address_space(1))) void*)(Ap + k0),
            (__attribute__((address_space(3))) void*)(AsB), 16, 0, 0);
        __builtin_amdgcn_global_load_lds(
            (const __attribute__((address_space(1))) void*)(Ap + k0 + (size_t)16 * 64),
            (__attribute__((address_space(3))) void*)(AsB + 16 * 32), 16, 0, 0);
        __builtin_amdgcn_global_load_lds(
            (const __attribute__((address_space(1))) void*)(Bp + k0),
            (__attribute__((address_space(3))) void*)(BsB), 16, 0, 0);
        __builtin_amdgcn_global_load_lds(
            (const __attribute__((address_space(1))) void*)(Bp + k0 + (size_t)16 * 64),
            (__attribute__((address_space(3))) void*)(BsB + 16 * 32), 16, 0, 0);
        __syncthreads();

        f16x8 af[4], bf[4];
        #pragma unroll
        for (int i = 0; i < 4; ++i) {
            const int r = wm * 64 + i * 16 + (lane & 15);
            const int p = (lane >> 4) ^ ((r >> 1) & 3);
            af[i] = *(const f16x8*)&As[r * 32 + p * 8];
        }
        #pragma unroll
        for (int j = 0; j < 4; ++j) {
            const int r = wn * 64 + j * 16 + (lane & 15);
            const int p = (lane >> 4) ^ ((r >> 1) & 3);
            bf[j] = *(const f16x8*)&Bs[r * 32 + p * 8];
        }
        #pragma unroll
        for (int i = 0; i < 4; ++i)
            #pragma unroll
            for (int j = 0; j < 4; ++j)
                acc[i][j] = __builtin_amdgcn_mfma_f32_16x16x32_f16(af[i], bf[j], acc[i][j], 0, 0, 0);
    }

    const int quad = lane >> 4, cc = lane & 15;
    #pragma unroll
    for (int i = 0; i < 4; ++i) {
        const int rl0 = wm * 64 + i * 16 + quad * 4;
        #pragma unroll
        for (int j = 0; j < 4; ++j) {
            const int col = wn * 64 + j * 16 + cc;
            #pragma unroll
            for (int r = 0; r < 4; ++r) {
                const int rl = rl0 + r;
                op[(size_t)rl * PM + col] =
                    (f16)(__expf(acc[i][j][r] - sqs[rl]) * MSCALE);
            }
        }
    }
}

// ---------------- KV partials over 8 n-chunks, s partials ----------------
__global__ __launch_bounds__(256) void kv_s_kernel(
        const f16* __restrict__ vh, const f16* __restrict__ kf,
        float* __restrict__ kvp, float* __restrict__ sbufp)
{
    __shared__ float vs[128][64];
    const int t = threadIdx.x;
    const int bh = blockIdx.x;
    const int nc = blockIdx.y;
    const int n0 = nc * 128;
    const int m = t & 127, dh = t >> 7;

    const f16* vb = vh + (((size_t)bh << 10) + n0) * 64;
    #pragma unroll
    for (int i = 0; i < 8; ++i) {
        int idx = i * 1024 + t * 4;
        f16x4 v4 = *(const f16x4*)&vb[idx];
        float4 vf = make_float4((float)v4.x, (float)v4.y, (float)v4.z, (float)v4.w);
        *(float4*)&vs[idx >> 6][idx & 63] = vf;
    }
    __syncthreads();

    float acc[32];
    #pragma unroll
    for (int j = 0; j < 32; ++j) acc[j] = 0.f;
    float sacc = 0.f;
    const f16* kfb = kf + (((size_t)bh << 10) + n0) * PM + m;
    #pragma unroll 8
    for (int nn = 0; nn < 128; ++nn) {
        float kq = (float)kfb[(size_t)nn * PM];
        sacc += kq;
        #pragma unroll
        for (int j = 0; j < 32; ++j)
            acc[j] += kq * vs[nn][dh * 32 + j];
    }

    float* kvo = kvp + (((size_t)(nc * 96 + bh) * PM + m)) * PD + dh * 32;
    #pragma unroll
    for (int j = 0; j < 32; ++j) kvo[j] = acc[j];
    if (dh == 0)
        sbufp[(size_t)(nc * 96 + bh) * PM + m] = sacc;
}

// ---------------- reduce 8 kv/s partials ----------------
__global__ __launch_bounds__(256) void kv_reduce(
        const float* __restrict__ kvp, const float* __restrict__ sbufp,
        float* __restrict__ kv, float* __restrict__ s)
{
    const int idx = blockIdx.x * 256 + threadIdx.x;  // 0..786431
    float a = 0.f;
    #pragma unroll
    for (int c = 0; c < 8; ++c) a += kvp[(size_t)c * 786432 + idx];
    kv[idx] = a;
    if (idx < 96 * PM) {
        float sa = 0.f;
        #pragma unroll
        for (int c = 0; c < 8; ++c) sa += sbufp[(size_t)c * 96 * PM + idx];
        s[idx] = sa;
    }
}

// ---------------- apply: oh = (qf @ KV) / (qf . s), plain f16 out [B,N,C] ----------------
__global__ __launch_bounds__(256) void apply_kernel(
        const f16* __restrict__ qf, const float* __restrict__ kv,
        const float* __restrict__ sv, f16* __restrict__ ohA)
{
    __shared__ float kvs[128][64];
    __shared__ float qfs[32][128];
    __shared__ float ss[128];
    __shared__ float part[32][8];
    __shared__ float dns[32];
    const int t = threadIdx.x;
    const int bh = blockIdx.x >> 5;
    const int n0 = (blockIdx.x & 31) * 32;
    const int b = bh / PH, h = bh % PH;

    const float* kv0 = kv + (size_t)bh * PM * PD;
    #pragma unroll
    for (int i = 0; i < 32; ++i) {
        int idx = i * 256 + t;
        kvs[idx >> 6][idx & 63] = kv0[idx];
    }
    const f16* qfb = qf + (((size_t)bh << 10) + n0) * PM;
    #pragma unroll
    for (int i = 0; i < 16; ++i) {
        int idx = i * 256 + t;
        qfs[idx >> 7][idx & 127] = (float)qfb[idx];
    }
    if (t < 128) ss[t] = sv[(size_t)bh * PM + t];
    __syncthreads();
    {
        const int row = t & 31, seg = t >> 5;
        float p = 0.f;
        #pragma unroll
        for (int mm = seg * 16; mm < seg * 16 + 16; ++mm)
            p += qfs[row][mm] * ss[mm];
        part[row][seg] = p;
    }
    __syncthreads();
    if (t < 32) {
        float dsum = 0.f;
        #pragma unroll
        for (int j = 0; j < 8; ++j) dsum += part[t][j];
        dns[t] = (dsum < 1e-12f) ? 1e-12f : dsum;
    }
    __syncthreads();

    const int d = t & 63, rg = t >> 6;
    float acc[8] = {0.f};
    for (int mm = 0; mm < 128; ++mm) {
        float kvv = kvs[mm][d];
        #pragma unroll
        for (int j = 0; j < 8; ++j)
            acc[j] += qfs[rg * 8 + j][mm] * kvv;
    }
    f16* ob = ohA + (size_t)(b * PN + n0) * PC + h * PD + d;
    #pragma unroll
    for (int j = 0; j < 8; ++j) {
        const int r = rg * 8 + j;
        ob[(size_t)r * PC] = (f16)(acc[j] / dns[r]);
    }
}

// ---------------- generic MFMA GEMM (for the output projection) ----------------
template<int BN>
__global__ __launch_bounds__(256) void gemm_mfma(
        const f16* __restrict__ A, int lda,
        const f16* __restrict__ Bm, int ldb,
        float* __restrict__ Cm, int ldc, int Kp,
        const float* __restrict__ bias)
{
    constexpr int JT = BN / 32;
    __shared__ f16 As[128 * 32];
    __shared__ f16 Bs[BN * 32];
    const int t = threadIdx.x;
    const int wave = t >> 6, lane = t & 63;
    const int wm = wave >> 1, wn = wave & 1;
    const int bi = blockIdx.y * 128, bj = blockIdx.x * BN;

    f32x4 acc[4][JT] = {};

    const int srow16 = lane >> 2;
    const int schunk = ((lane & 3) ^ ((lane >> 3) & 3)) * 8;
    const f16* Ap = A + (size_t)(bi + wave * 32 + srow16) * lda + schunk;
    f16* AsB = &As[wave * 32 * 32];
    const int brow0 = (BN == 128) ? wave * 32 : wave * 16;
    const f16* Bp = Bm + (size_t)(bj + brow0 + srow16) * ldb + schunk;
    f16* BsB = &Bs[brow0 * 32];

    const int nK = Kp / 32;
    for (int kt = 0; kt < nK; ++kt) {
        const int k0 = kt * 32;
        __syncthreads();
        __builtin_amdgcn_global_load_lds(
            (const __attribute__((address_space(1))) void*)(Ap + k0),
            (__attribute__((address_space(3))) void*)(AsB), 16, 0, 0);
        __builtin_amdgcn_global_load_lds(
            (const __attribute__((address_space(1))) void*)(Ap + k0 + (size_t)16 * lda),
            (__attribute__((address_space(3))) void*)(AsB + 16 * 32), 16, 0, 0);
        __builtin_amdgcn_global_load_lds(
            (const __attribute__((address_space(1))) void*)(Bp + k0),
            (__attribute__((address_space(3))) void*)(BsB), 16, 0, 0);
        if (BN == 128)
            __builtin_amdgcn_global_load_lds(
                (const __attribute__((address_space(1))) void*)(Bp + k0 + (size_t)16 * ldb),
                (__attribute__((address_space(3))) void*)(BsB + 16 * 32), 16, 0, 0);
        __syncthreads();

        f16x8 af[4], bf[JT];
        #pragma unroll
        for (int i = 0; i < 4; ++i) {
            const int r = wm * 64 + i * 16 + (lane & 15);
            const int p = (lane >> 4) ^ ((r >> 1) & 3);
            af[i] = *(const f16x8*)&As[r * 32 + p * 8];
        }
        #pragma unroll
        for (int j = 0; j < JT; ++j) {
            const int r = wn * (BN / 2) + j * 16 + (lane & 15);
            const int p = (lane >> 4) ^ ((r >> 1) & 3);
            bf[j] = *(const f16x8*)&Bs[r * 32 + p * 8];
        }
        #pragma unroll
        for (int i = 0; i < 4; ++i)
            #pragma unroll
            for (int j = 0; j < JT; ++j)
                acc[i][j] = __builtin_amdgcn_mfma_f32_16x16x32_f16(af[i], bf[j], acc[i][j], 0, 0, 0);
    }

    const int cr = (lane >> 4) * 4, cc = lane & 15;
    #pragma unroll
    for (int i = 0; i < 4; ++i) {
        const int row = bi + wm * 64 + i * 16 + cr;
        #pragma unroll
        for (int j = 0; j < JT; ++j) {
            const int col = bj + wn * (BN / 2) + j * 16 + cc;
            const float bv = bias ? bias[col] : 0.f;
            #pragma unroll
            for (int r = 0; r < 4; ++r)
                Cm[(size_t)(row + r) * ldc + col] = acc[i][j][r] + bv;
        }
    }
}

extern "C" void kernel_launch(void* const* d_in, const int* in_sizes, int n_in,
                              void* d_out, int out_size, void* d_ws, size_t ws_size,
                              hipStream_t stream) {
    const float* x      = (const float*)d_in[0];  // [B,N,C]
    const float* qkv_w  = (const float*)d_in[1];  // [3C,C]
    const float* proj_w = (const float*)d_in[2];  // [C,C]
    const float* proj_b = (const float*)d_in[3];  // [C]
    const float* rm     = (const float*)d_in[4];  // [H,D,M]
    float* out = (float*)d_out;                    // [B,N,C] = 25,165,824 B

    char* ws = (char*)d_ws;
    f16*   Ax   = (f16*)(ws);                     // [8192][768]      = 12,582,912
    f16*   Bqk  = (f16*)(ws + 12582912);          // [2304][768]      =  3,538,944
    f16*   Bp   = (f16*)(ws + 16121856);          // [768][768]       =  1,179,648
    f16*   Rt   = (f16*)(ws + 17301504);          // [12][128][64]    =    196,608
    f16*   zq   = (f16*)(ws + 17498112);          // [96][1024][64]   = 12,582,912
    f16*   zk   = (f16*)(ws + 30081024);          // [96][1024][64]   = 12,582,912
    f16*   vh   = (f16*)(ws + 42663936);          // [96][1024][64]   = 12,582,912
    float* sqq  = (float*)(ws + 55246848);        // [96][1024] f32   =    393,216
    float* sqk  = (float*)(ws + 55640064);        // [96][1024] f32   =    393,216
    f16*   qf   = (f16*)(ws + 56033280);          // [96][1024][128]  = 25,165,824
    f16*   kf   = (f16*)(ws + 81199104);          // [96][1024][128]  = 25,165,824
    float* sbufp= (float*)(ws + 106364928);       // [8][96][128] f32 =    393,216
    float* kvf  = (float*)(ws + 106758144);       // [96][128][64] f32=  3,145,728
    float* sf   = (float*)(ws + 109903872);       // [96][128] f32    =     49,152
    f16*   ohA  = (f16*)(ws + 109953024);         // [8192][768]      = 12,582,912
    // kv partials live in d_out (dead until final gemm): [8][96][128][64] f32
    float* kvp = (float*)d_out;

    // 1) conversions
    conv_hi<<<8192, 192, 0, stream>>>(x, Ax, PC);
    conv_hi<<<2304, 192, 0, stream>>>(qkv_w, Bqk, PC);
    conv_hi<<<768, 192, 0, stream>>>(proj_w, Bp, PC);
    conv_rt<<<PH, 256, 0, stream>>>(rm, Rt);

    // 2) fused qkv projection -> z_q, z_k (f16+sqnorm), v (f16)
    gemm_qkv<<<dim3(18, 64), 256, 0, stream>>>(Ax, Bqk, zq, zk, vh, sqq, sqk);

    // 3) feature maps via MFMA (exp fused in epilogue)
    feat_gemm<<<dim3(8, 96, 2), 256, 0, stream>>>(zq, zk, Rt, sqq, sqk, qf, kf);

    // 4) KV/s partials (8 n-chunks) -> reduce
    kv_s_kernel<<<dim3(96, 8), 256, 0, stream>>>(vh, kf, kvp, sbufp);
    kv_reduce<<<3072, 256, 0, stream>>>(kvp, sbufp, kvf, sf);

    // 5) apply + fused denom, writes plain f16 oh [B,N,C]
    apply_kernel<<<96 * 32, 256, 0, stream>>>(qf, kvf, sf, ohA);

    // 6) out = oh @ proj_w^T + proj_b, BN=64 tiles, K=768
    gemm_mfma<64><<<dim3(12, 64), 256, 0, stream>>>(ohA, PC, Bp, PC,
                                                    out, PC, PC, proj_b);
}

// Round 7
// 202.251 us; speedup vs baseline: 4.1707x; 1.3997x over previous
//
#include <hip/hip_runtime.h>
#include <hip/hip_bf16.h>

// Problem constants: B=8, N=1024, C=768, H=12, D=64, M=128
#define PB 8
#define PN 1024
#define PC 768
#define PH 12
#define PD 64
#define PM 128
#define SQ 0.35355339059327373f      // (D^-0.5)^0.5 = D^-0.25
#define MSCALE 0.08838834764831843f  // M^-0.5

typedef _Float16 f16;
typedef f16 f16x8 __attribute__((ext_vector_type(8)));
typedef f16 f16x4 __attribute__((ext_vector_type(4)));
typedef float f32x4 __attribute__((ext_vector_type(4)));

// ---------------- conversion: fp32 -> f16 ----------------
__global__ __launch_bounds__(192) void conv_hi(const float* __restrict__ src,
                                               f16* __restrict__ dst, int cols) {
    const int r = blockIdx.x;
    const int c = threadIdx.x * 4;
    float4 v = *(const float4*)&src[(size_t)r * cols + c];
    f16x4 hi;
    hi.x = (f16)v.x; hi.y = (f16)v.y; hi.z = (f16)v.z; hi.w = (f16)v.w;
    *(f16x4*)&dst[(size_t)r * cols + c] = hi;
}

// Rt[h][m][d] = (f16) rm[h][d][m]  (transpose per head)
__global__ __launch_bounds__(256) void conv_rt(const float* __restrict__ rm,
                                               f16* __restrict__ Rt) {
    const int h = blockIdx.x;
    for (int e = threadIdx.x; e < PD * PM; e += 256) {
        int m = e >> 6, d = e & 63;
        Rt[(size_t)h * PD * PM + e] = (f16)rm[(size_t)h * PD * PM + d * PM + m];
    }
}

// ---------------- fused qkv GEMM: emits z_q, z_k (f16, scaled), v (f16), sqnorms ----------------
__global__ __launch_bounds__(256) void gemm_qkv(
        const f16* __restrict__ A,    // [8192][768]
        const f16* __restrict__ Bm,   // [2304][768]
        f16* __restrict__ zq, f16* __restrict__ zk, f16* __restrict__ vh,
        float* __restrict__ sqq, float* __restrict__ sqk)
{
    __shared__ f16 As[128 * 32];
    __shared__ f16 Bs[128 * 32];
    const int t = threadIdx.x;
    const int wave = t >> 6, lane = t & 63;
    const int wm = wave >> 1, wn = wave & 1;
    const int bi = blockIdx.y * 128, bj = blockIdx.x * 128;

    f32x4 acc[4][4] = {};

    const int srow16 = lane >> 2;
    const int schunk = ((lane & 3) ^ ((lane >> 3) & 3)) * 8;
    const f16* Ap = A + (size_t)(bi + wave * 32 + srow16) * PC + schunk;
    f16* AsB = &As[wave * 32 * 32];
    const f16* Bp = Bm + (size_t)(bj + wave * 32 + srow16) * PC + schunk;
    f16* BsB = &Bs[wave * 32 * 32];

    for (int kt = 0; kt < 24; ++kt) {
        const int k0 = kt * 32;
        __syncthreads();
        __builtin_amdgcn_global_load_lds(
            (const __attribute__((address_space(1))) void*)(Ap + k0),
            (__attribute__((address_space(3))) void*)(AsB), 16, 0, 0);
        __builtin_amdgcn_global_load_lds(
            (const __attribute__((address_space(1))) void*)(Ap + k0 + (size_t)16 * PC),
            (__attribute__((address_space(3))) void*)(AsB + 16 * 32), 16, 0, 0);
        __builtin_amdgcn_global_load_lds(
            (const __attribute__((address_space(1))) void*)(Bp + k0),
            (__attribute__((address_space(3))) void*)(BsB), 16, 0, 0);
        __builtin_amdgcn_global_load_lds(
            (const __attribute__((address_space(1))) void*)(Bp + k0 + (size_t)16 * PC),
            (__attribute__((address_space(3))) void*)(BsB + 16 * 32), 16, 0, 0);
        __syncthreads();

        f16x8 af[4], bf[4];
        #pragma unroll
        for (int i = 0; i < 4; ++i) {
            const int r = wm * 64 + i * 16 + (lane & 15);
            const int p = (lane >> 4) ^ ((r >> 1) & 3);
            af[i] = *(const f16x8*)&As[r * 32 + p * 8];
        }
        #pragma unroll
        for (int j = 0; j < 4; ++j) {
            const int r = wn * 64 + j * 16 + (lane & 15);
            const int p = (lane >> 4) ^ ((r >> 1) & 3);
            bf[j] = *(const f16x8*)&Bs[r * 32 + p * 8];
        }
        #pragma unroll
        for (int i = 0; i < 4; ++i)
            #pragma unroll
            for (int j = 0; j < 4; ++j)
                acc[i][j] = __builtin_amdgcn_mfma_f32_16x16x32_f16(af[i], bf[j], acc[i][j], 0, 0, 0);
    }

    const int quad = lane >> 4, cc = lane & 15;
    const int colbase = bj + wn * 64;
    const int b = bi >> 10;
    if (colbase < 1536) {
        const int which = colbase >= 768;
        const int h = (colbase - which * 768) >> 6;
        f16* zdst = which ? zk : zq;
        float* sdst = which ? sqk : sqq;
        const size_t bh = (size_t)(b * PH + h);
        #pragma unroll
        for (int i = 0; i < 4; ++i) {
            const int row0 = bi + wm * 64 + i * 16 + quad * 4;
            #pragma unroll
            for (int r = 0; r < 4; ++r) {
                const int n = (row0 + r) & 1023;
                f16 zh[4]; float psq = 0.f;
                #pragma unroll
                for (int j = 0; j < 4; ++j) {
                    zh[j] = (f16)(acc[i][j][r] * SQ);
                    float zf = (float)zh[j];
                    psq += zf * zf;
                }
                psq += __shfl_xor(psq, 1, 64);
                psq += __shfl_xor(psq, 2, 64);
                psq += __shfl_xor(psq, 4, 64);
                psq += __shfl_xor(psq, 8, 64);
                if (cc == 0) sdst[(bh << 10) + n] = 0.5f * psq;
                f16* zp = zdst + (((bh << 10) + n) << 6);
                #pragma unroll
                for (int j = 0; j < 4; ++j) zp[j * 16 + cc] = zh[j];
            }
        }
    } else {
        const int h = (colbase - 1536) >> 6;
        const size_t bh = (size_t)(b * PH + h);
        #pragma unroll
        for (int i = 0; i < 4; ++i) {
            const int row0 = bi + wm * 64 + i * 16 + quad * 4;
            #pragma unroll
            for (int r = 0; r < 4; ++r) {
                const int n = (row0 + r) & 1023;
                f16* vp = vh + (((bh << 10) + n) << 6);
                #pragma unroll
                for (int j = 0; j < 4; ++j) vp[j * 16 + cc] = (f16)acc[i][j][r];
            }
        }
    }
}

// ---------------- fused feat(k) + kf^T@V partial + colsum partial ----------------
// grid (8 n-tiles, 96 bh); 256 thr. P tile (128x128) lives only in LDS.
__global__ __launch_bounds__(256) void feat_kv(
        const f16* __restrict__ zk, const f16* __restrict__ Rt,
        const float* __restrict__ sqk, const f16* __restrict__ vh,
        float* __restrict__ kvp, float* __restrict__ sbufp)
{
    __shared__ __align__(16) char smem[52224];
    f16* As = (f16*)smem;              // stage z (8KB)
    f16* Bs = (f16*)(smem + 8192);     // stage Rt (8KB)
    f16* Pt = (f16*)smem;              // [128 m][136 n] (34816B) - aliases stages
    f16* vT = (f16*)(smem + 34816);    // [64 d][136 n]  (17408B)
    __shared__ float sqs[128];

    const int t = threadIdx.x;
    const int wave = t >> 6, lane = t & 63;
    const int wm = wave >> 1, wn = wave & 1;
    const int nt = blockIdx.x, bh = blockIdx.y;
    const int h = bh % PH;

    const f16* A = zk + (((size_t)bh << 10) + nt * 128) * 64;
    const f16* Bm = Rt + (size_t)h * (PM * PD);

    if (t < 128) sqs[t] = sqk[((size_t)bh << 10) + nt * 128 + t];

    f32x4 acc[4][4] = {};
    const int srow16 = lane >> 2;
    const int schunk = ((lane & 3) ^ ((lane >> 3) & 3)) * 8;
    const f16* Ap = A + (size_t)(wave * 32 + srow16) * 64 + schunk;
    f16* AsB = &As[wave * 32 * 32];
    const f16* Bp = Bm + (size_t)(wave * 32 + srow16) * 64 + schunk;
    f16* BsB = &Bs[wave * 32 * 32];

    #pragma unroll
    for (int kt = 0; kt < 2; ++kt) {
        const int k0 = kt * 32;
        __syncthreads();
        __builtin_amdgcn_global_load_lds(
            (const __attribute__((address_space(1))) void*)(Ap + k0),
            (__attribute__((address_space(3))) void*)(AsB), 16, 0, 0);
        __builtin_amdgcn_global_load_lds(
            (const __attribute__((address_space(1))) void*)(Ap + k0 + (size_t)16 * 64),
            (__attribute__((address_space(3))) void*)(AsB + 16 * 32), 16, 0, 0);
        __builtin_amdgcn_global_load_lds(
            (const __attribute__((address_space(1))) void*)(Bp + k0),
            (__attribute__((address_space(3))) void*)(BsB), 16, 0, 0);
        __builtin_amdgcn_global_load_lds(
            (const __attribute__((address_space(1))) void*)(Bp + k0 + (size_t)16 * 64),
            (__attribute__((address_space(3))) void*)(BsB + 16 * 32), 16, 0, 0);
        __syncthreads();

        f16x8 af[4], bf[4];
        #pragma unroll
        for (int i = 0; i < 4; ++i) {
            const int r = wm * 64 + i * 16 + (lane & 15);
            const int p = (lane >> 4) ^ ((r >> 1) & 3);
            af[i] = *(const f16x8*)&As[r * 32 + p * 8];
        }
        #pragma unroll
        for (int j = 0; j < 4; ++j) {
            const int r = wn * 64 + j * 16 + (lane & 15);
            const int p = (lane >> 4) ^ ((r >> 1) & 3);
            bf[j] = *(const f16x8*)&Bs[r * 32 + p * 8];
        }
        #pragma unroll
        for (int i = 0; i < 4; ++i)
            #pragma unroll
            for (int j = 0; j < 4; ++j)
                acc[i][j] = __builtin_amdgcn_mfma_f32_16x16x32_f16(af[i], bf[j], acc[i][j], 0, 0, 0);
    }

    const int quad = lane >> 4, cc = lane & 15;
    __syncthreads();   // all stage reads done; safe to overwrite with Pt

    // P transposed: Pt[m][n] = exp(logit - sq)*MSCALE
    #pragma unroll
    for (int i = 0; i < 4; ++i) {
        #pragma unroll
        for (int j = 0; j < 4; ++j) {
            const int col = wn * 64 + j * 16 + cc;
            #pragma unroll
            for (int r = 0; r < 4; ++r) {
                const int rl = wm * 64 + i * 16 + quad * 4 + r;
                Pt[col * 136 + rl] = (f16)(__expf(acc[i][j][r] - sqs[rl]) * MSCALE);
            }
        }
    }
    // stage v transposed: vT[d][n]
    {
        const int vn = t >> 1;
        const int vhf = (t & 1) * 32;
        const f16* vbase = vh + (((size_t)bh << 10) + nt * 128 + vn) * 64 + vhf;
        #pragma unroll
        for (int k = 0; k < 4; ++k) {
            f16x8 vv = *(const f16x8*)&vbase[k * 8];
            #pragma unroll
            for (int e = 0; e < 8; ++e)
                vT[(vhf + k * 8 + e) * 136 + vn] = vv[e];
        }
    }
    __syncthreads();

    // C2[m][d] = sum_n Pt[m][n] * v[n][d]
    f32x4 acc2[4][2] = {};
    #pragma unroll
    for (int kt = 0; kt < 4; ++kt) {
        const int kb = kt * 32 + (lane >> 4) * 8;
        f16x8 af2[4], bf2[2];
        #pragma unroll
        for (int i = 0; i < 4; ++i)
            af2[i] = *(const f16x8*)&Pt[(wm * 64 + i * 16 + (lane & 15)) * 136 + kb];
        #pragma unroll
        for (int j = 0; j < 2; ++j)
            bf2[j] = *(const f16x8*)&vT[(wn * 32 + j * 16 + (lane & 15)) * 136 + kb];
        #pragma unroll
        for (int i = 0; i < 4; ++i)
            #pragma unroll
            for (int j = 0; j < 2; ++j)
                acc2[i][j] = __builtin_amdgcn_mfma_f32_16x16x32_f16(af2[i], bf2[j], acc2[i][j], 0, 0, 0);
    }

    float* kvo = kvp + (size_t)(nt * 96 + bh) * 8192;
    #pragma unroll
    for (int i = 0; i < 4; ++i) {
        #pragma unroll
        for (int j = 0; j < 2; ++j) {
            const int d = wn * 32 + j * 16 + cc;
            #pragma unroll
            for (int r = 0; r < 4; ++r) {
                const int m = wm * 64 + i * 16 + quad * 4 + r;
                kvo[m * 64 + d] = acc2[i][j][r];
            }
        }
    }
    // s partial: sum_n Pt[m][n]
    {
        const int sm = t >> 1, shf = (t & 1) * 64;
        float sp = 0.f;
        #pragma unroll
        for (int k = 0; k < 8; ++k) {
            f16x8 pv = *(const f16x8*)&Pt[sm * 136 + shf + k * 8];
            #pragma unroll
            for (int e = 0; e < 8; ++e) sp += (float)pv[e];
        }
        sp += __shfl_xor(sp, 1, 64);
        if ((t & 1) == 0) sbufp[(size_t)(nt * 96 + bh) * 128 + sm] = sp;
    }
}

// ---------------- reduce 8 kv/s partials ----------------
__global__ __launch_bounds__(256) void kv_reduce(
        const float* __restrict__ kvp, const float* __restrict__ sbufp,
        float* __restrict__ kv, float* __restrict__ s)
{
    const int idx = blockIdx.x * 256 + threadIdx.x;  // 0..786431
    float a = 0.f;
    #pragma unroll
    for (int c = 0; c < 8; ++c) a += kvp[(size_t)c * 786432 + idx];
    kv[idx] = a;
    if (idx < 96 * PM) {
        float sa = 0.f;
        #pragma unroll
        for (int c = 0; c < 8; ++c) sa += sbufp[(size_t)c * 96 * PM + idx];
        s[idx] = sa;
    }
}

// ---------------- fused feat(q) + denom + P@KV + divide -> ohA f16 [B,N,C] ----------------
__global__ __launch_bounds__(256) void feat_apply(
        const f16* __restrict__ zq, const f16* __restrict__ Rt,
        const float* __restrict__ sqq, const float* __restrict__ kvf,
        const float* __restrict__ sf, f16* __restrict__ ohA)
{
    __shared__ __align__(16) char smem[52224];
    f16* As = (f16*)smem;
    f16* Bs = (f16*)(smem + 8192);
    f16* Pn = (f16*)smem;              // [128 n][136 m]
    f16* kvT = (f16*)(smem + 34816);   // [64 d][136 m]
    __shared__ float sqs[128], ssm[128], dns[128];

    const int t = threadIdx.x;
    const int wave = t >> 6, lane = t & 63;
    const int wm = wave >> 1, wn = wave & 1;
    const int nt = blockIdx.x, bh = blockIdx.y;
    const int b = bh / PH, h = bh % PH;

    const f16* A = zq + (((size_t)bh << 10) + nt * 128) * 64;
    const f16* Bm = Rt + (size_t)h * (PM * PD);

    if (t < 128) {
        sqs[t] = sqq[((size_t)bh << 10) + nt * 128 + t];
        ssm[t] = sf[(size_t)bh * 128 + t];
    }

    f32x4 acc[4][4] = {};
    const int srow16 = lane >> 2;
    const int schunk = ((lane & 3) ^ ((lane >> 3) & 3)) * 8;
    const f16* Ap = A + (size_t)(wave * 32 + srow16) * 64 + schunk;
    f16* AsB = &As[wave * 32 * 32];
    const f16* Bp = Bm + (size_t)(wave * 32 + srow16) * 64 + schunk;
    f16* BsB = &Bs[wave * 32 * 32];

    #pragma unroll
    for (int kt = 0; kt < 2; ++kt) {
        const int k0 = kt * 32;
        __syncthreads();
        __builtin_amdgcn_global_load_lds(
            (const __attribute__((address_space(1))) void*)(Ap + k0),
            (__attribute__((address_space(3))) void*)(AsB), 16, 0, 0);
        __builtin_amdgcn_global_load_lds(
            (const __attribute__((address_space(1))) void*)(Ap + k0 + (size_t)16 * 64),
            (__attribute__((address_space(3))) void*)(AsB + 16 * 32), 16, 0, 0);
        __builtin_amdgcn_global_load_lds(
            (const __attribute__((address_space(1))) void*)(Bp + k0),
            (__attribute__((address_space(3))) void*)(BsB), 16, 0, 0);
        __builtin_amdgcn_global_load_lds(
            (const __attribute__((address_space(1))) void*)(Bp + k0 + (size_t)16 * 64),
            (__attribute__((address_space(3))) void*)(BsB + 16 * 32), 16, 0, 0);
        __syncthreads();

        f16x8 af[4], bf[4];
        #pragma unroll
        for (int i = 0; i < 4; ++i) {
            const int r = wm * 64 + i * 16 + (lane & 15);
            const int p = (lane >> 4) ^ ((r >> 1) & 3);
            af[i] = *(const f16x8*)&As[r * 32 + p * 8];
        }
        #pragma unroll
        for (int j = 0; j < 4; ++j) {
            const int r = wn * 64 + j * 16 + (lane & 15);
            const int p = (lane >> 4) ^ ((r >> 1) & 3);
            bf[j] = *(const f16x8*)&Bs[r * 32 + p * 8];
        }
        #pragma unroll
        for (int i = 0; i < 4; ++i)
            #pragma unroll
            for (int j = 0; j < 4; ++j)
                acc[i][j] = __builtin_amdgcn_mfma_f32_16x16x32_f16(af[i], bf[j], acc[i][j], 0, 0, 0);
    }

    const int quad = lane >> 4, cc = lane & 15;
    __syncthreads();

    // P natural layout: Pn[n][m]
    #pragma unroll
    for (int i = 0; i < 4; ++i) {
        #pragma unroll
        for (int j = 0; j < 4; ++j) {
            const int col = wn * 64 + j * 16 + cc;
            #pragma unroll
            for (int r = 0; r < 4; ++r) {
                const int rl = wm * 64 + i * 16 + quad * 4 + r;
                Pn[rl * 136 + col] = (f16)(__expf(acc[i][j][r] - sqs[rl]) * MSCALE);
            }
        }
    }
    // stage KV transposed + f16: kvT[d][m]
    {
        const int m = t >> 1;
        const int dh2 = (t & 1) * 32;
        const float* kvb = kvf + ((size_t)bh * 128 + m) * 64 + dh2;
        #pragma unroll
        for (int k = 0; k < 8; ++k) {
            float4 k4 = *(const float4*)&kvb[k * 4];
            kvT[(dh2 + k * 4 + 0) * 136 + m] = (f16)k4.x;
            kvT[(dh2 + k * 4 + 1) * 136 + m] = (f16)k4.y;
            kvT[(dh2 + k * 4 + 2) * 136 + m] = (f16)k4.z;
            kvT[(dh2 + k * 4 + 3) * 136 + m] = (f16)k4.w;
        }
    }
    __syncthreads();

    // dn[n] = sum_m Pn[n][m] * ssm[m]
    {
        const int n = t >> 1, mh = (t & 1) * 64;
        float p = 0.f;
        #pragma unroll
        for (int k = 0; k < 8; ++k) {
            f16x8 pv = *(const f16x8*)&Pn[n * 136 + mh + k * 8];
            #pragma unroll
            for (int e = 0; e < 8; ++e)
                p += (float)pv[e] * ssm[mh + k * 8 + e];
        }
        p += __shfl_xor(p, 1, 64);
        if ((t & 1) == 0) dns[n] = (p < 1e-12f) ? 1e-12f : p;
    }
    __syncthreads();

    // C3[n][d] = sum_m Pn[n][m] * KV[m][d]
    f32x4 acc3[4][2] = {};
    #pragma unroll
    for (int kt = 0; kt < 4; ++kt) {
        const int kb = kt * 32 + (lane >> 4) * 8;
        f16x8 af3[4], bf3[2];
        #pragma unroll
        for (int i = 0; i < 4; ++i)
            af3[i] = *(const f16x8*)&Pn[(wm * 64 + i * 16 + (lane & 15)) * 136 + kb];
        #pragma unroll
        for (int j = 0; j < 2; ++j)
            bf3[j] = *(const f16x8*)&kvT[(wn * 32 + j * 16 + (lane & 15)) * 136 + kb];
        #pragma unroll
        for (int i = 0; i < 4; ++i)
            #pragma unroll
            for (int j = 0; j < 2; ++j)
                acc3[i][j] = __builtin_amdgcn_mfma_f32_16x16x32_f16(af3[i], bf3[j], acc3[i][j], 0, 0, 0);
    }

    f16* ob = ohA + ((size_t)(b * PN) + nt * 128) * PC + h * PD;
    #pragma unroll
    for (int i = 0; i < 4; ++i) {
        #pragma unroll
        for (int j = 0; j < 2; ++j) {
            const int d = wn * 32 + j * 16 + cc;
            #pragma unroll
            for (int r = 0; r < 4; ++r) {
                const int n = wm * 64 + i * 16 + quad * 4 + r;
                ob[(size_t)n * PC + d] = (f16)(acc3[i][j][r] / dns[n]);
            }
        }
    }
}

// ---------------- generic MFMA GEMM (output projection) ----------------
template<int BN>
__global__ __launch_bounds__(256) void gemm_mfma(
        const f16* __restrict__ A, int lda,
        const f16* __restrict__ Bm, int ldb,
        float* __restrict__ Cm, int ldc, int Kp,
        const float* __restrict__ bias)
{
    constexpr int JT = BN / 32;
    __shared__ f16 As[128 * 32];
    __shared__ f16 Bs[BN * 32];
    const int t = threadIdx.x;
    const int wave = t >> 6, lane = t & 63;
    const int wm = wave >> 1, wn = wave & 1;
    const int bi = blockIdx.y * 128, bj = blockIdx.x * BN;

    f32x4 acc[4][JT] = {};

    const int srow16 = lane >> 2;
    const int schunk = ((lane & 3) ^ ((lane >> 3) & 3)) * 8;
    const f16* Ap = A + (size_t)(bi + wave * 32 + srow16) * lda + schunk;
    f16* AsB = &As[wave * 32 * 32];
    const int brow0 = (BN == 128) ? wave * 32 : wave * 16;
    const f16* Bp = Bm + (size_t)(bj + brow0 + srow16) * ldb + schunk;
    f16* BsB = &Bs[brow0 * 32];

    const int nK = Kp / 32;
    for (int kt = 0; kt < nK; ++kt) {
        const int k0 = kt * 32;
        __syncthreads();
        __builtin_amdgcn_global_load_lds(
            (const __attribute__((address_space(1))) void*)(Ap + k0),
            (__attribute__((address_space(3))) void*)(AsB), 16, 0, 0);
        __builtin_amdgcn_global_load_lds(
            (const __attribute__((address_space(1))) void*)(Ap + k0 + (size_t)16 * lda),
            (__attribute__((address_space(3))) void*)(AsB + 16 * 32), 16, 0, 0);
        __builtin_amdgcn_global_load_lds(
            (const __attribute__((address_space(1))) void*)(Bp + k0),
            (__attribute__((address_space(3))) void*)(BsB), 16, 0, 0);
        if (BN == 128)
            __builtin_amdgcn_global_load_lds(
                (const __attribute__((address_space(1))) void*)(Bp + k0 + (size_t)16 * ldb),
                (__attribute__((address_space(3))) void*)(BsB + 16 * 32), 16, 0, 0);
        __syncthreads();

        f16x8 af[4], bf[JT];
        #pragma unroll
        for (int i = 0; i < 4; ++i) {
            const int r = wm * 64 + i * 16 + (lane & 15);
            const int p = (lane >> 4) ^ ((r >> 1) & 3);
            af[i] = *(const f16x8*)&As[r * 32 + p * 8];
        }
        #pragma unroll
        for (int j = 0; j < JT; ++j) {
            const int r = wn * (BN / 2) + j * 16 + (lane & 15);
            const int p = (lane >> 4) ^ ((r >> 1) & 3);
            bf[j] = *(const f16x8*)&Bs[r * 32 + p * 8];
        }
        #pragma unroll
        for (int i = 0; i < 4; ++i)
            #pragma unroll
            for (int j = 0; j < JT; ++j)
                acc[i][j] = __builtin_amdgcn_mfma_f32_16x16x32_f16(af[i], bf[j], acc[i][j], 0, 0, 0);
    }

    const int cr = (lane >> 4) * 4, cc = lane & 15;
    #pragma unroll
    for (int i = 0; i < 4; ++i) {
        const int row = bi + wm * 64 + i * 16 + cr;
        #pragma unroll
        for (int j = 0; j < JT; ++j) {
            const int col = bj + wn * (BN / 2) + j * 16 + cc;
            const float bv = bias ? bias[col] : 0.f;
            #pragma unroll
            for (int r = 0; r < 4; ++r)
                Cm[(size_t)(row + r) * ldc + col] = acc[i][j][r] + bv;
        }
    }
}

extern "C" void kernel_launch(void* const* d_in, const int* in_sizes, int n_in,
                              void* d_out, int out_size, void* d_ws, size_t ws_size,
                              hipStream_t stream) {
    const float* x      = (const float*)d_in[0];
    const float* qkv_w  = (const float*)d_in[1];
    const float* proj_w = (const float*)d_in[2];
    const float* proj_b = (const float*)d_in[3];
    const float* rm     = (const float*)d_in[4];
    float* out = (float*)d_out;

    char* ws = (char*)d_ws;
    f16*   Ax   = (f16*)(ws);                     // [8192][768]      = 12,582,912
    f16*   Bqk  = (f16*)(ws + 12582912);          // [2304][768]      =  3,538,944
    f16*   Bp   = (f16*)(ws + 16121856);          // [768][768]       =  1,179,648
    f16*   Rt   = (f16*)(ws + 17301504);          // [12][128][64]    =    196,608
    f16*   zq   = (f16*)(ws + 17498112);          // [96][1024][64]   = 12,582,912
    f16*   zk   = (f16*)(ws + 30081024);          // [96][1024][64]   = 12,582,912
    f16*   vh   = (f16*)(ws + 42663936);          // [96][1024][64]   = 12,582,912
    float* sqq  = (float*)(ws + 55246848);        // [96][1024] f32   =    393,216
    float* sqk  = (float*)(ws + 55640064);        // [96][1024] f32   =    393,216
    float* sbufp= (float*)(ws + 56033280);        // [8][96][128] f32 =    393,216
    float* kvf  = (float*)(ws + 56426496);        // [96][128][64] f32=  3,145,728
    float* sf   = (float*)(ws + 59572224);        // [96][128] f32    =     49,152
    f16*   ohA  = (f16*)(ws + 59621376);          // [8192][768]      = 12,582,912
    // kv partials in d_out (dead until final gemm): [8][96][128][64] f32
    float* kvp = (float*)d_out;

    // 1) conversions
    conv_hi<<<8192, 192, 0, stream>>>(x, Ax, PC);
    conv_hi<<<2304, 192, 0, stream>>>(qkv_w, Bqk, PC);
    conv_hi<<<768, 192, 0, stream>>>(proj_w, Bp, PC);
    conv_rt<<<PH, 256, 0, stream>>>(rm, Rt);

    // 2) fused qkv projection -> z_q, z_k (f16+sqnorm), v (f16)
    gemm_qkv<<<dim3(18, 64), 256, 0, stream>>>(Ax, Bqk, zq, zk, vh, sqq, sqk);

    // 3) fused feat(k) + kf^T@V partials + colsum partials
    feat_kv<<<dim3(8, 96), 256, 0, stream>>>(zk, Rt, sqk, vh, kvp, sbufp);
    kv_reduce<<<3072, 256, 0, stream>>>(kvp, sbufp, kvf, sf);

    // 4) fused feat(q) + denom + P@KV -> ohA
    feat_apply<<<dim3(8, 96), 256, 0, stream>>>(zq, Rt, sqq, kvf, sf, ohA);

    // 5) out = oh @ proj_w^T + proj_b
    gemm_mfma<64><<<dim3(12, 64), 256, 0, stream>>>(ohA, PC, Bp, PC,
                                                    out, PC, PC, proj_b);
}

// Round 8
// 189.502 us; speedup vs baseline: 4.4512x; 1.0673x over previous
//
#include <hip/hip_runtime.h>
#include <hip/hip_bf16.h>

// Problem constants: B=8, N=1024, C=768, H=12, D=64, M=128
#define PB 8
#define PN 1024
#define PC 768
#define PH 12
#define PD 64
#define PM 128
#define SQ 0.35355339059327373f      // (D^-0.5)^0.5 = D^-0.25
#define MSCALE 0.08838834764831843f  // M^-0.5

typedef _Float16 f16;
typedef f16 f16x8 __attribute__((ext_vector_type(8)));
typedef f16 f16x4 __attribute__((ext_vector_type(4)));
typedef float f32x4 __attribute__((ext_vector_type(4)));

#define GLL(src, dst) __builtin_amdgcn_global_load_lds( \
    (const __attribute__((address_space(1))) void*)(src), \
    (__attribute__((address_space(3))) void*)(dst), 16, 0, 0)

// ---------------- all conversions in one launch ----------------
// blocks [0,8192): x; [8192,10496): qkv_w; [10496,11264): proj_w; [11264,11276): Rt
__global__ __launch_bounds__(192) void conv_all(
        const float* __restrict__ x, const float* __restrict__ qkv_w,
        const float* __restrict__ proj_w, const float* __restrict__ rm,
        f16* __restrict__ Ax, f16* __restrict__ Bqk, f16* __restrict__ Bp,
        f16* __restrict__ Rt)
{
    const int bid = blockIdx.x;
    const int t = threadIdx.x;
    if (bid < 11264) {
        const float* src; f16* dst; int r;
        if (bid < 8192)       { src = x;      dst = Ax;  r = bid; }
        else if (bid < 10496) { src = qkv_w;  dst = Bqk; r = bid - 8192; }
        else                  { src = proj_w; dst = Bp;  r = bid - 10496; }
        const int c = t * 4;
        float4 v = *(const float4*)&src[(size_t)r * PC + c];
        f16x4 hv;
        hv.x = (f16)v.x; hv.y = (f16)v.y; hv.z = (f16)v.z; hv.w = (f16)v.w;
        *(f16x4*)&dst[(size_t)r * PC + c] = hv;
    } else {
        const int h = bid - 11264;
        for (int e = t; e < PD * PM; e += 192)
            Rt[(size_t)h * 8192 + e] = (f16)rm[(size_t)h * 8192 + (e & 63) * PM + (e >> 6)];
    }
}

// ---------------- fused qkv GEMM (BK=64): emits z_q, z_k (f16), v (f16), sqnorms ----------------
__global__ __launch_bounds__(256) void gemm_qkv(
        const f16* __restrict__ A,    // [8192][768]
        const f16* __restrict__ Bm,   // [2304][768]
        f16* __restrict__ zq, f16* __restrict__ zk, f16* __restrict__ vh,
        float* __restrict__ sqq, float* __restrict__ sqk)
{
    __shared__ f16 As[128 * 64];
    __shared__ f16 Bs[128 * 64];
    const int t = threadIdx.x;
    const int wave = t >> 6, lane = t & 63;
    const int wm = wave >> 1, wn = wave & 1;
    const int bi = blockIdx.y * 128, bj = blockIdx.x * 128;

    f32x4 acc[4][4] = {};

    // staging: per issue a wave fills 8 rows x 128B; src chunk = (l&7)^((l>>4)&3), odd issue ^4
    const int rowi = lane >> 3;
    const int cb = (lane & 7) ^ ((lane >> 4) & 3);
    const f16* ApE = A + (size_t)(bi + wave * 32 + rowi) * PC + cb * 8;
    const f16* ApO = A + (size_t)(bi + wave * 32 + rowi) * PC + (cb ^ 4) * 8;
    const f16* BpE = Bm + (size_t)(bj + wave * 32 + rowi) * PC + cb * 8;
    const f16* BpO = Bm + (size_t)(bj + wave * 32 + rowi) * PC + (cb ^ 4) * 8;
    f16* AsB = &As[wave * 32 * 64];
    f16* BsB = &Bs[wave * 32 * 64];

    const int q4 = lane >> 4;
    for (int kt = 0; kt < 12; ++kt) {
        const int k0 = kt * 64;
        __syncthreads();
        GLL(ApE + k0,               AsB);
        GLL(ApO + k0 + (size_t) 8 * PC, AsB + 8 * 64);
        GLL(ApE + k0 + (size_t)16 * PC, AsB + 16 * 64);
        GLL(ApO + k0 + (size_t)24 * PC, AsB + 24 * 64);
        GLL(BpE + k0,               BsB);
        GLL(BpO + k0 + (size_t) 8 * PC, BsB + 8 * 64);
        GLL(BpE + k0 + (size_t)16 * PC, BsB + 16 * 64);
        GLL(BpO + k0 + (size_t)24 * PC, BsB + 24 * 64);
        __syncthreads();

        #pragma unroll
        for (int kh = 0; kh < 2; ++kh) {
            f16x8 af[4], bf[4];
            #pragma unroll
            for (int i = 0; i < 4; ++i) {
                const int r = wm * 64 + i * 16 + (lane & 15);
                const int p = (kh * 4 + q4) ^ ((r >> 1) & 7);
                af[i] = *(const f16x8*)&As[r * 64 + p * 8];
            }
            #pragma unroll
            for (int j = 0; j < 4; ++j) {
                const int r = wn * 64 + j * 16 + (lane & 15);
                const int p = (kh * 4 + q4) ^ ((r >> 1) & 7);
                bf[j] = *(const f16x8*)&Bs[r * 64 + p * 8];
            }
            #pragma unroll
            for (int i = 0; i < 4; ++i)
                #pragma unroll
                for (int j = 0; j < 4; ++j)
                    acc[i][j] = __builtin_amdgcn_mfma_f32_16x16x32_f16(af[i], bf[j], acc[i][j], 0, 0, 0);
        }
    }

    const int quad = lane >> 4, cc = lane & 15;
    const int colbase = bj + wn * 64;
    const int b = bi >> 10;
    if (colbase < 1536) {
        const int which = colbase >= 768;
        const int h = (colbase - which * 768) >> 6;
        f16* zdst = which ? zk : zq;
        float* sdst = which ? sqk : sqq;
        const size_t bh = (size_t)(b * PH + h);
        #pragma unroll
        for (int i = 0; i < 4; ++i) {
            const int row0 = bi + wm * 64 + i * 16 + quad * 4;
            #pragma unroll
            for (int r = 0; r < 4; ++r) {
                const int n = (row0 + r) & 1023;
                f16 zh[4]; float psq = 0.f;
                #pragma unroll
                for (int j = 0; j < 4; ++j) {
                    zh[j] = (f16)(acc[i][j][r] * SQ);
                    float zf = (float)zh[j];
                    psq += zf * zf;
                }
                psq += __shfl_xor(psq, 1, 64);
                psq += __shfl_xor(psq, 2, 64);
                psq += __shfl_xor(psq, 4, 64);
                psq += __shfl_xor(psq, 8, 64);
                if (cc == 0) sdst[(bh << 10) + n] = 0.5f * psq;
                f16* zp = zdst + (((bh << 10) + n) << 6);
                #pragma unroll
                for (int j = 0; j < 4; ++j) zp[j * 16 + cc] = zh[j];
            }
        }
    } else {
        const int h = (colbase - 1536) >> 6;
        const size_t bh = (size_t)(b * PH + h);
        #pragma unroll
        for (int i = 0; i < 4; ++i) {
            const int row0 = bi + wm * 64 + i * 16 + quad * 4;
            #pragma unroll
            for (int r = 0; r < 4; ++r) {
                const int n = (row0 + r) & 1023;
                f16* vp = vh + (((bh << 10) + n) << 6);
                #pragma unroll
                for (int j = 0; j < 4; ++j) vp[j * 16 + cc] = (f16)acc[i][j][r];
            }
        }
    }
}

// ---------------- fused feat(k) + kf^T@V partial + colsum partial (BK=64, 1 stage) ----------------
__global__ __launch_bounds__(256) void feat_kv(
        const f16* __restrict__ zk, const f16* __restrict__ Rt,
        const float* __restrict__ sqk, const f16* __restrict__ vh,
        float* __restrict__ kvp, float* __restrict__ sbufp)
{
    __shared__ __align__(16) char smem[52224];
    f16* As = (f16*)smem;              // stage z [128][64] (16KB)
    f16* Bs = (f16*)(smem + 16384);    // stage Rt [128][64] (16KB)
    f16* Pt = (f16*)smem;              // [128 m][136 n] (34816B) aliases stages
    f16* vT = (f16*)(smem + 34816);    // [64 d][136 n] (17408B)
    __shared__ float sqs[128];

    const int t = threadIdx.x;
    const int wave = t >> 6, lane = t & 63;
    const int wm = wave >> 1, wn = wave & 1;
    const int nt = blockIdx.x, bh = blockIdx.y;
    const int h = bh % PH;

    const f16* A = zk + (((size_t)bh << 10) + nt * 128) * 64;
    const f16* Bm = Rt + (size_t)h * (PM * PD);

    if (t < 128) sqs[t] = sqk[((size_t)bh << 10) + nt * 128 + t];

    const int rowi = lane >> 3;
    const int cb = (lane & 7) ^ ((lane >> 4) & 3);
    const f16* ApE = A + (size_t)(wave * 32 + rowi) * 64 + cb * 8;
    const f16* ApO = A + (size_t)(wave * 32 + rowi) * 64 + (cb ^ 4) * 8;
    const f16* BpE = Bm + (size_t)(wave * 32 + rowi) * 64 + cb * 8;
    const f16* BpO = Bm + (size_t)(wave * 32 + rowi) * 64 + (cb ^ 4) * 8;
    f16* AsB = &As[wave * 32 * 64];
    f16* BsB = &Bs[wave * 32 * 64];
    GLL(ApE,            AsB);
    GLL(ApO + 8 * 64,   AsB + 8 * 64);
    GLL(ApE + 16 * 64,  AsB + 16 * 64);
    GLL(ApO + 24 * 64,  AsB + 24 * 64);
    GLL(BpE,            BsB);
    GLL(BpO + 8 * 64,   BsB + 8 * 64);
    GLL(BpE + 16 * 64,  BsB + 16 * 64);
    GLL(BpO + 24 * 64,  BsB + 24 * 64);
    __syncthreads();

    const int q4 = lane >> 4;
    f32x4 acc[4][4] = {};
    #pragma unroll
    for (int kh = 0; kh < 2; ++kh) {
        f16x8 af[4], bf[4];
        #pragma unroll
        for (int i = 0; i < 4; ++i) {
            const int r = wm * 64 + i * 16 + (lane & 15);
            const int p = (kh * 4 + q4) ^ ((r >> 1) & 7);
            af[i] = *(const f16x8*)&As[r * 64 + p * 8];
        }
        #pragma unroll
        for (int j = 0; j < 4; ++j) {
            const int r = wn * 64 + j * 16 + (lane & 15);
            const int p = (kh * 4 + q4) ^ ((r >> 1) & 7);
            bf[j] = *(const f16x8*)&Bs[r * 64 + p * 8];
        }
        #pragma unroll
        for (int i = 0; i < 4; ++i)
            #pragma unroll
            for (int j = 0; j < 4; ++j)
                acc[i][j] = __builtin_amdgcn_mfma_f32_16x16x32_f16(af[i], bf[j], acc[i][j], 0, 0, 0);
    }

    const int quad = lane >> 4, cc = lane & 15;
    __syncthreads();   // stage reads done; safe to overwrite with Pt

    #pragma unroll
    for (int i = 0; i < 4; ++i) {
        #pragma unroll
        for (int j = 0; j < 4; ++j) {
            const int col = wn * 64 + j * 16 + cc;
            #pragma unroll
            for (int r = 0; r < 4; ++r) {
                const int rl = wm * 64 + i * 16 + quad * 4 + r;
                Pt[col * 136 + rl] = (f16)(__expf(acc[i][j][r] - sqs[rl]) * MSCALE);
            }
        }
    }
    {
        const int vn = t >> 1;
        const int vhf = (t & 1) * 32;
        const f16* vbase = vh + (((size_t)bh << 10) + nt * 128 + vn) * 64 + vhf;
        #pragma unroll
        for (int k = 0; k < 4; ++k) {
            f16x8 vv = *(const f16x8*)&vbase[k * 8];
            #pragma unroll
            for (int e = 0; e < 8; ++e)
                vT[(vhf + k * 8 + e) * 136 + vn] = vv[e];
        }
    }
    __syncthreads();

    f32x4 acc2[4][2] = {};
    #pragma unroll
    for (int kt = 0; kt < 4; ++kt) {
        const int kb = kt * 32 + (lane >> 4) * 8;
        f16x8 af2[4], bf2[2];
        #pragma unroll
        for (int i = 0; i < 4; ++i)
            af2[i] = *(const f16x8*)&Pt[(wm * 64 + i * 16 + (lane & 15)) * 136 + kb];
        #pragma unroll
        for (int j = 0; j < 2; ++j)
            bf2[j] = *(const f16x8*)&vT[(wn * 32 + j * 16 + (lane & 15)) * 136 + kb];
        #pragma unroll
        for (int i = 0; i < 4; ++i)
            #pragma unroll
            for (int j = 0; j < 2; ++j)
                acc2[i][j] = __builtin_amdgcn_mfma_f32_16x16x32_f16(af2[i], bf2[j], acc2[i][j], 0, 0, 0);
    }

    float* kvo = kvp + (size_t)(nt * 96 + bh) * 8192;
    #pragma unroll
    for (int i = 0; i < 4; ++i) {
        #pragma unroll
        for (int j = 0; j < 2; ++j) {
            const int d = wn * 32 + j * 16 + cc;
            #pragma unroll
            for (int r = 0; r < 4; ++r) {
                const int m = wm * 64 + i * 16 + quad * 4 + r;
                kvo[m * 64 + d] = acc2[i][j][r];
            }
        }
    }
    {
        const int sm = t >> 1, shf = (t & 1) * 64;
        float sp = 0.f;
        #pragma unroll
        for (int k = 0; k < 8; ++k) {
            f16x8 pv = *(const f16x8*)&Pt[sm * 136 + shf + k * 8];
            #pragma unroll
            for (int e = 0; e < 8; ++e) sp += (float)pv[e];
        }
        sp += __shfl_xor(sp, 1, 64);
        if ((t & 1) == 0) sbufp[(size_t)(nt * 96 + bh) * 128 + sm] = sp;
    }
}

// ---------------- reduce 8 kv/s partials ----------------
__global__ __launch_bounds__(256) void kv_reduce(
        const float* __restrict__ kvp, const float* __restrict__ sbufp,
        float* __restrict__ kv, float* __restrict__ s)
{
    const int idx = blockIdx.x * 256 + threadIdx.x;
    float a = 0.f;
    #pragma unroll
    for (int c = 0; c < 8; ++c) a += kvp[(size_t)c * 786432 + idx];
    kv[idx] = a;
    if (idx < 96 * PM) {
        float sa = 0.f;
        #pragma unroll
        for (int c = 0; c < 8; ++c) sa += sbufp[(size_t)c * 96 * PM + idx];
        s[idx] = sa;
    }
}

// ---------------- fused feat(q) + denom + P@KV + divide (BK=64, 1 stage) ----------------
__global__ __launch_bounds__(256) void feat_apply(
        const f16* __restrict__ zq, const f16* __restrict__ Rt,
        const float* __restrict__ sqq, const float* __restrict__ kvf,
        const float* __restrict__ sf, f16* __restrict__ ohA)
{
    __shared__ __align__(16) char smem[52224];
    f16* As = (f16*)smem;
    f16* Bs = (f16*)(smem + 16384);
    f16* Pn = (f16*)smem;              // [128 n][136 m]
    f16* kvT = (f16*)(smem + 34816);   // [64 d][136 m]
    __shared__ float sqs[128], ssm[128], dns[128];

    const int t = threadIdx.x;
    const int wave = t >> 6, lane = t & 63;
    const int wm = wave >> 1, wn = wave & 1;
    const int nt = blockIdx.x, bh = blockIdx.y;
    const int b = bh / PH, h = bh % PH;

    const f16* A = zq + (((size_t)bh << 10) + nt * 128) * 64;
    const f16* Bm = Rt + (size_t)h * (PM * PD);

    if (t < 128) {
        sqs[t] = sqq[((size_t)bh << 10) + nt * 128 + t];
        ssm[t] = sf[(size_t)bh * 128 + t];
    }

    const int rowi = lane >> 3;
    const int cb = (lane & 7) ^ ((lane >> 4) & 3);
    const f16* ApE = A + (size_t)(wave * 32 + rowi) * 64 + cb * 8;
    const f16* ApO = A + (size_t)(wave * 32 + rowi) * 64 + (cb ^ 4) * 8;
    const f16* BpE = Bm + (size_t)(wave * 32 + rowi) * 64 + cb * 8;
    const f16* BpO = Bm + (size_t)(wave * 32 + rowi) * 64 + (cb ^ 4) * 8;
    f16* AsB = &As[wave * 32 * 64];
    f16* BsB = &Bs[wave * 32 * 64];
    GLL(ApE,            AsB);
    GLL(ApO + 8 * 64,   AsB + 8 * 64);
    GLL(ApE + 16 * 64,  AsB + 16 * 64);
    GLL(ApO + 24 * 64,  AsB + 24 * 64);
    GLL(BpE,            BsB);
    GLL(BpO + 8 * 64,   BsB + 8 * 64);
    GLL(BpE + 16 * 64,  BsB + 16 * 64);
    GLL(BpO + 24 * 64,  BsB + 24 * 64);
    __syncthreads();

    const int q4 = lane >> 4;
    f32x4 acc[4][4] = {};
    #pragma unroll
    for (int kh = 0; kh < 2; ++kh) {
        f16x8 af[4], bf[4];
        #pragma unroll
        for (int i = 0; i < 4; ++i) {
            const int r = wm * 64 + i * 16 + (lane & 15);
            const int p = (kh * 4 + q4) ^ ((r >> 1) & 7);
            af[i] = *(const f16x8*)&As[r * 64 + p * 8];
        }
        #pragma unroll
        for (int j = 0; j < 4; ++j) {
            const int r = wn * 64 + j * 16 + (lane & 15);
            const int p = (kh * 4 + q4) ^ ((r >> 1) & 7);
            bf[j] = *(const f16x8*)&Bs[r * 64 + p * 8];
        }
        #pragma unroll
        for (int i = 0; i < 4; ++i)
            #pragma unroll
            for (int j = 0; j < 4; ++j)
                acc[i][j] = __builtin_amdgcn_mfma_f32_16x16x32_f16(af[i], bf[j], acc[i][j], 0, 0, 0);
    }

    const int quad = lane >> 4, cc = lane & 15;
    __syncthreads();

    #pragma unroll
    for (int i = 0; i < 4; ++i) {
        #pragma unroll
        for (int j = 0; j < 4; ++j) {
            const int col = wn * 64 + j * 16 + cc;
            #pragma unroll
            for (int r = 0; r < 4; ++r) {
                const int rl = wm * 64 + i * 16 + quad * 4 + r;
                Pn[rl * 136 + col] = (f16)(__expf(acc[i][j][r] - sqs[rl]) * MSCALE);
            }
        }
    }
    {
        const int m = t >> 1;
        const int dh2 = (t & 1) * 32;
        const float* kvb = kvf + ((size_t)bh * 128 + m) * 64 + dh2;
        #pragma unroll
        for (int k = 0; k < 8; ++k) {
            float4 k4 = *(const float4*)&kvb[k * 4];
            kvT[(dh2 + k * 4 + 0) * 136 + m] = (f16)k4.x;
            kvT[(dh2 + k * 4 + 1) * 136 + m] = (f16)k4.y;
            kvT[(dh2 + k * 4 + 2) * 136 + m] = (f16)k4.z;
            kvT[(dh2 + k * 4 + 3) * 136 + m] = (f16)k4.w;
        }
    }
    __syncthreads();

    {
        const int n = t >> 1, mh = (t & 1) * 64;
        float p = 0.f;
        #pragma unroll
        for (int k = 0; k < 8; ++k) {
            f16x8 pv = *(const f16x8*)&Pn[n * 136 + mh + k * 8];
            #pragma unroll
            for (int e = 0; e < 8; ++e)
                p += (float)pv[e] * ssm[mh + k * 8 + e];
        }
        p += __shfl_xor(p, 1, 64);
        if ((t & 1) == 0) dns[n] = (p < 1e-12f) ? 1e-12f : p;
    }
    __syncthreads();

    f32x4 acc3[4][2] = {};
    #pragma unroll
    for (int kt = 0; kt < 4; ++kt) {
        const int kb = kt * 32 + (lane >> 4) * 8;
        f16x8 af3[4], bf3[2];
        #pragma unroll
        for (int i = 0; i < 4; ++i)
            af3[i] = *(const f16x8*)&Pn[(wm * 64 + i * 16 + (lane & 15)) * 136 + kb];
        #pragma unroll
        for (int j = 0; j < 2; ++j)
            bf3[j] = *(const f16x8*)&kvT[(wn * 32 + j * 16 + (lane & 15)) * 136 + kb];
        #pragma unroll
        for (int i = 0; i < 4; ++i)
            #pragma unroll
            for (int j = 0; j < 2; ++j)
                acc3[i][j] = __builtin_amdgcn_mfma_f32_16x16x32_f16(af3[i], bf3[j], acc3[i][j], 0, 0, 0);
    }

    f16* ob = ohA + ((size_t)(b * PN) + nt * 128) * PC + h * PD;
    #pragma unroll
    for (int i = 0; i < 4; ++i) {
        #pragma unroll
        for (int j = 0; j < 2; ++j) {
            const int d = wn * 32 + j * 16 + cc;
            #pragma unroll
            for (int r = 0; r < 4; ++r) {
                const int n = wm * 64 + i * 16 + quad * 4 + r;
                ob[(size_t)n * PC + d] = (f16)(acc3[i][j][r] / dns[n]);
            }
        }
    }
}

// ---------------- output projection GEMM (BK=64, BN=64) ----------------
__global__ __launch_bounds__(256) void gemm_proj(
        const f16* __restrict__ A,    // [8192][768]
        const f16* __restrict__ Bm,   // [768][768]
        float* __restrict__ Cm, const float* __restrict__ bias)
{
    __shared__ f16 As[128 * 64];
    __shared__ f16 Bs[64 * 64];
    const int t = threadIdx.x;
    const int wave = t >> 6, lane = t & 63;
    const int wm = wave >> 1, wn = wave & 1;
    const int bi = blockIdx.y * 128, bj = blockIdx.x * 64;

    f32x4 acc[4][2] = {};

    const int rowi = lane >> 3;
    const int cb = (lane & 7) ^ ((lane >> 4) & 3);
    const f16* ApE = A + (size_t)(bi + wave * 32 + rowi) * PC + cb * 8;
    const f16* ApO = A + (size_t)(bi + wave * 32 + rowi) * PC + (cb ^ 4) * 8;
    const f16* BpE = Bm + (size_t)(bj + wave * 16 + rowi) * PC + cb * 8;
    const f16* BpO = Bm + (size_t)(bj + wave * 16 + rowi) * PC + (cb ^ 4) * 8;
    f16* AsB = &As[wave * 32 * 64];
    f16* BsB = &Bs[wave * 16 * 64];

    const int q4 = lane >> 4;
    for (int kt = 0; kt < 12; ++kt) {
        const int k0 = kt * 64;
        __syncthreads();
        GLL(ApE + k0,               AsB);
        GLL(ApO + k0 + (size_t) 8 * PC, AsB + 8 * 64);
        GLL(ApE + k0 + (size_t)16 * PC, AsB + 16 * 64);
        GLL(ApO + k0 + (size_t)24 * PC, AsB + 24 * 64);
        GLL(BpE + k0,               BsB);
        GLL(BpO + k0 + (size_t) 8 * PC, BsB + 8 * 64);
        __syncthreads();

        #pragma unroll
        for (int kh = 0; kh < 2; ++kh) {
            f16x8 af[4], bf[2];
            #pragma unroll
            for (int i = 0; i < 4; ++i) {
                const int r = wm * 64 + i * 16 + (lane & 15);
                const int p = (kh * 4 + q4) ^ ((r >> 1) & 7);
                af[i] = *(const f16x8*)&As[r * 64 + p * 8];
            }
            #pragma unroll
            for (int j = 0; j < 2; ++j) {
                const int r = wn * 32 + j * 16 + (lane & 15);
                const int p = (kh * 4 + q4) ^ ((r >> 1) & 7);
                bf[j] = *(const f16x8*)&Bs[r * 64 + p * 8];
            }
            #pragma unroll
            for (int i = 0; i < 4; ++i)
                #pragma unroll
                for (int j = 0; j < 2; ++j)
                    acc[i][j] = __builtin_amdgcn_mfma_f32_16x16x32_f16(af[i], bf[j], acc[i][j], 0, 0, 0);
        }
    }

    const int cr = (lane >> 4) * 4, cc = lane & 15;
    #pragma unroll
    for (int i = 0; i < 4; ++i) {
        const int row = bi + wm * 64 + i * 16 + cr;
        #pragma unroll
        for (int j = 0; j < 2; ++j) {
            const int col = bj + wn * 32 + j * 16 + cc;
            const float bv = bias[col];
            #pragma unroll
            for (int r = 0; r < 4; ++r)
                Cm[(size_t)(row + r) * PC + col] = acc[i][j][r] + bv;
        }
    }
}

extern "C" void kernel_launch(void* const* d_in, const int* in_sizes, int n_in,
                              void* d_out, int out_size, void* d_ws, size_t ws_size,
                              hipStream_t stream) {
    const float* x      = (const float*)d_in[0];
    const float* qkv_w  = (const float*)d_in[1];
    const float* proj_w = (const float*)d_in[2];
    const float* proj_b = (const float*)d_in[3];
    const float* rm     = (const float*)d_in[4];
    float* out = (float*)d_out;

    char* ws = (char*)d_ws;
    f16*   Ax   = (f16*)(ws);                     // [8192][768]      = 12,582,912
    f16*   Bqk  = (f16*)(ws + 12582912);          // [2304][768]      =  3,538,944
    f16*   Bp   = (f16*)(ws + 16121856);          // [768][768]       =  1,179,648
    f16*   Rt   = (f16*)(ws + 17301504);          // [12][128][64]    =    196,608
    f16*   zq   = (f16*)(ws + 17498112);          // [96][1024][64]   = 12,582,912
    f16*   zk   = (f16*)(ws + 30081024);          // [96][1024][64]   = 12,582,912
    f16*   vh   = (f16*)(ws + 42663936);          // [96][1024][64]   = 12,582,912
    float* sqq  = (float*)(ws + 55246848);        // [96][1024] f32   =    393,216
    float* sqk  = (float*)(ws + 55640064);        // [96][1024] f32   =    393,216
    float* sbufp= (float*)(ws + 56033280);        // [8][96][128] f32 =    393,216
    float* kvf  = (float*)(ws + 56426496);        // [96][128][64] f32=  3,145,728
    float* sf   = (float*)(ws + 59572224);        // [96][128] f32    =     49,152
    f16*   ohA  = (f16*)(ws + 59621376);          // [8192][768]      = 12,582,912
    float* kvp = (float*)d_out;                   // partials in d_out (dead until gemm_proj)

    // 1) all conversions in one launch
    conv_all<<<11276, 192, 0, stream>>>(x, qkv_w, proj_w, rm, Ax, Bqk, Bp, Rt);

    // 2) fused qkv projection -> z_q, z_k (f16+sqnorm), v (f16)
    gemm_qkv<<<dim3(18, 64), 256, 0, stream>>>(Ax, Bqk, zq, zk, vh, sqq, sqk);

    // 3) fused feat(k) + kf^T@V partials + colsum partials
    feat_kv<<<dim3(8, 96), 256, 0, stream>>>(zk, Rt, sqk, vh, kvp, sbufp);
    kv_reduce<<<3072, 256, 0, stream>>>(kvp, sbufp, kvf, sf);

    // 4) fused feat(q) + denom + P@KV -> ohA
    feat_apply<<<dim3(8, 96), 256, 0, stream>>>(zq, Rt, sqq, kvf, sf, ohA);

    // 5) out = oh @ proj_w^T + proj_b
    gemm_proj<<<dim3(12, 64), 256, 0, stream>>>(ohA, Bp, out, proj_b);
}

// Round 9
// 187.464 us; speedup vs baseline: 4.4996x; 1.0109x over previous
//
#include <hip/hip_runtime.h>
#include <hip/hip_bf16.h>

// Problem constants: B=8, N=1024, C=768, H=12, D=64, M=128
#define PB 8
#define PN 1024
#define PC 768
#define PH 12
#define PD 64
#define PM 128
#define SQ 0.35355339059327373f      // (D^-0.5)^0.5 = D^-0.25
#define MSCALE 0.08838834764831843f  // M^-0.5

typedef _Float16 f16;
typedef f16 f16x8 __attribute__((ext_vector_type(8)));
typedef f16 f16x4 __attribute__((ext_vector_type(4)));
typedef float f32x4 __attribute__((ext_vector_type(4)));

#define GLL(src, dst) __builtin_amdgcn_global_load_lds( \
    (const __attribute__((address_space(1))) void*)(src), \
    (__attribute__((address_space(3))) void*)(dst), 16, 0, 0)

// ---------------- conversions + scratch zero-init, one launch ----------------
// [0,8192): x; [8192,10496): qkv_w; [10496,11264): proj_w; [11264,11276): Rt;
// [11276,12300): zero kvf (1024 blocks x 768 f32); [12300,12316): zero sf
__global__ __launch_bounds__(192) void conv_all(
        const float* __restrict__ x, const float* __restrict__ qkv_w,
        const float* __restrict__ proj_w, const float* __restrict__ rm,
        f16* __restrict__ Ax, f16* __restrict__ Bqk, f16* __restrict__ Bp,
        f16* __restrict__ Rt, float* __restrict__ kvf, float* __restrict__ sf)
{
    const int bid = blockIdx.x;
    const int t = threadIdx.x;
    if (bid < 11264) {
        const float* src; f16* dst; int r;
        if (bid < 8192)       { src = x;      dst = Ax;  r = bid; }
        else if (bid < 10496) { src = qkv_w;  dst = Bqk; r = bid - 8192; }
        else                  { src = proj_w; dst = Bp;  r = bid - 10496; }
        const int c = t * 4;
        float4 v = *(const float4*)&src[(size_t)r * PC + c];
        f16x4 hv;
        hv.x = (f16)v.x; hv.y = (f16)v.y; hv.z = (f16)v.z; hv.w = (f16)v.w;
        *(f16x4*)&dst[(size_t)r * PC + c] = hv;
    } else if (bid < 11276) {
        const int h = bid - 11264;
        for (int e = t; e < PD * PM; e += 192)
            Rt[(size_t)h * 8192 + e] = (f16)rm[(size_t)h * 8192 + (e & 63) * PM + (e >> 6)];
    } else if (bid < 12300) {
        float4 z = make_float4(0.f, 0.f, 0.f, 0.f);
        *(float4*)&kvf[(size_t)(bid - 11276) * 768 + t * 4] = z;
    } else {
        float4 z = make_float4(0.f, 0.f, 0.f, 0.f);
        *(float4*)&sf[(size_t)(bid - 12300) * 768 + t * 4] = z;
    }
}

// ---------------- fused qkv GEMM (BK=64): emits z_q, z_k, v (f16), sqnorms ----------------
// grid (64 row-tiles, 18 col-tiles): blocks sharing an A row-tile are spaced 64
// apart in linear ID -> same XCD -> A-tile served from one L2.
__global__ __launch_bounds__(256) void gemm_qkv(
        const f16* __restrict__ A,    // [8192][768]
        const f16* __restrict__ Bm,   // [2304][768]
        f16* __restrict__ zq, f16* __restrict__ zk, f16* __restrict__ vh,
        float* __restrict__ sqq, float* __restrict__ sqk)
{
    __shared__ f16 As[128 * 64];
    __shared__ f16 Bs[128 * 64];
    const int t = threadIdx.x;
    const int wave = t >> 6, lane = t & 63;
    const int wm = wave >> 1, wn = wave & 1;
    const int bi = blockIdx.x * 128, bj = blockIdx.y * 128;

    f32x4 acc[4][4] = {};

    const int rowi = lane >> 3;
    const int cb = (lane & 7) ^ ((lane >> 4) & 3);
    const f16* ApE = A + (size_t)(bi + wave * 32 + rowi) * PC + cb * 8;
    const f16* ApO = A + (size_t)(bi + wave * 32 + rowi) * PC + (cb ^ 4) * 8;
    const f16* BpE = Bm + (size_t)(bj + wave * 32 + rowi) * PC + cb * 8;
    const f16* BpO = Bm + (size_t)(bj + wave * 32 + rowi) * PC + (cb ^ 4) * 8;
    f16* AsB = &As[wave * 32 * 64];
    f16* BsB = &Bs[wave * 32 * 64];

    const int q4 = lane >> 4;
    for (int kt = 0; kt < 12; ++kt) {
        const int k0 = kt * 64;
        __syncthreads();
        GLL(ApE + k0,               AsB);
        GLL(ApO + k0 + (size_t) 8 * PC, AsB + 8 * 64);
        GLL(ApE + k0 + (size_t)16 * PC, AsB + 16 * 64);
        GLL(ApO + k0 + (size_t)24 * PC, AsB + 24 * 64);
        GLL(BpE + k0,               BsB);
        GLL(BpO + k0 + (size_t) 8 * PC, BsB + 8 * 64);
        GLL(BpE + k0 + (size_t)16 * PC, BsB + 16 * 64);
        GLL(BpO + k0 + (size_t)24 * PC, BsB + 24 * 64);
        __syncthreads();

        #pragma unroll
        for (int kh = 0; kh < 2; ++kh) {
            f16x8 af[4], bf[4];
            #pragma unroll
            for (int i = 0; i < 4; ++i) {
                const int r = wm * 64 + i * 16 + (lane & 15);
                const int p = (kh * 4 + q4) ^ ((r >> 1) & 7);
                af[i] = *(const f16x8*)&As[r * 64 + p * 8];
            }
            #pragma unroll
            for (int j = 0; j < 4; ++j) {
                const int r = wn * 64 + j * 16 + (lane & 15);
                const int p = (kh * 4 + q4) ^ ((r >> 1) & 7);
                bf[j] = *(const f16x8*)&Bs[r * 64 + p * 8];
            }
            #pragma unroll
            for (int i = 0; i < 4; ++i)
                #pragma unroll
                for (int j = 0; j < 4; ++j)
                    acc[i][j] = __builtin_amdgcn_mfma_f32_16x16x32_f16(af[i], bf[j], acc[i][j], 0, 0, 0);
        }
    }

    const int quad = lane >> 4, cc = lane & 15;
    const int colbase = bj + wn * 64;
    const int b = bi >> 10;
    if (colbase < 1536) {
        const int which = colbase >= 768;
        const int h = (colbase - which * 768) >> 6;
        f16* zdst = which ? zk : zq;
        float* sdst = which ? sqk : sqq;
        const size_t bh = (size_t)(b * PH + h);
        #pragma unroll
        for (int i = 0; i < 4; ++i) {
            const int row0 = bi + wm * 64 + i * 16 + quad * 4;
            #pragma unroll
            for (int r = 0; r < 4; ++r) {
                const int n = (row0 + r) & 1023;
                f16 zh[4]; float psq = 0.f;
                #pragma unroll
                for (int j = 0; j < 4; ++j) {
                    zh[j] = (f16)(acc[i][j][r] * SQ);
                    float zf = (float)zh[j];
                    psq += zf * zf;
                }
                psq += __shfl_xor(psq, 1, 64);
                psq += __shfl_xor(psq, 2, 64);
                psq += __shfl_xor(psq, 4, 64);
                psq += __shfl_xor(psq, 8, 64);
                if (cc == 0) sdst[(bh << 10) + n] = 0.5f * psq;
                f16* zp = zdst + (((bh << 10) + n) << 6);
                #pragma unroll
                for (int j = 0; j < 4; ++j) zp[j * 16 + cc] = zh[j];
            }
        }
    } else {
        const int h = (colbase - 1536) >> 6;
        const size_t bh = (size_t)(b * PH + h);
        #pragma unroll
        for (int i = 0; i < 4; ++i) {
            const int row0 = bi + wm * 64 + i * 16 + quad * 4;
            #pragma unroll
            for (int r = 0; r < 4; ++r) {
                const int n = (row0 + r) & 1023;
                f16* vp = vh + (((bh << 10) + n) << 6);
                #pragma unroll
                for (int j = 0; j < 4; ++j) vp[j * 16 + cc] = (f16)acc[i][j][r];
            }
        }
    }
}

// ---------------- fused feat(k) + kf^T@V partial + colsum, atomicAdd into kvf/sf ----------------
__global__ __launch_bounds__(256) void feat_kv(
        const f16* __restrict__ zk, const f16* __restrict__ Rt,
        const float* __restrict__ sqk, const f16* __restrict__ vh,
        float* __restrict__ kvf, float* __restrict__ sf)
{
    __shared__ __align__(16) char smem[52224];
    f16* As = (f16*)smem;              // stage z [128][64] (16KB)
    f16* Bs = (f16*)(smem + 16384);    // stage Rt [128][64] (16KB)
    f16* Pt = (f16*)smem;              // [128 m][136 n] aliases stages
    f16* vT = (f16*)(smem + 34816);    // [64 d][136 n]
    __shared__ float sqs[128];

    const int t = threadIdx.x;
    const int wave = t >> 6, lane = t & 63;
    const int wm = wave >> 1, wn = wave & 1;
    const int nt = blockIdx.x, bh = blockIdx.y;
    const int h = bh % PH;

    const f16* A = zk + (((size_t)bh << 10) + nt * 128) * 64;
    const f16* Bm = Rt + (size_t)h * (PM * PD);

    if (t < 128) sqs[t] = sqk[((size_t)bh << 10) + nt * 128 + t];

    const int rowi = lane >> 3;
    const int cb = (lane & 7) ^ ((lane >> 4) & 3);
    const f16* ApE = A + (size_t)(wave * 32 + rowi) * 64 + cb * 8;
    const f16* ApO = A + (size_t)(wave * 32 + rowi) * 64 + (cb ^ 4) * 8;
    const f16* BpE = Bm + (size_t)(wave * 32 + rowi) * 64 + cb * 8;
    const f16* BpO = Bm + (size_t)(wave * 32 + rowi) * 64 + (cb ^ 4) * 8;
    f16* AsB = &As[wave * 32 * 64];
    f16* BsB = &Bs[wave * 32 * 64];
    GLL(ApE,            AsB);
    GLL(ApO + 8 * 64,   AsB + 8 * 64);
    GLL(ApE + 16 * 64,  AsB + 16 * 64);
    GLL(ApO + 24 * 64,  AsB + 24 * 64);
    GLL(BpE,            BsB);
    GLL(BpO + 8 * 64,   BsB + 8 * 64);
    GLL(BpE + 16 * 64,  BsB + 16 * 64);
    GLL(BpO + 24 * 64,  BsB + 24 * 64);
    __syncthreads();

    const int q4 = lane >> 4;
    f32x4 acc[4][4] = {};
    #pragma unroll
    for (int kh = 0; kh < 2; ++kh) {
        f16x8 af[4], bf[4];
        #pragma unroll
        for (int i = 0; i < 4; ++i) {
            const int r = wm * 64 + i * 16 + (lane & 15);
            const int p = (kh * 4 + q4) ^ ((r >> 1) & 7);
            af[i] = *(const f16x8*)&As[r * 64 + p * 8];
        }
        #pragma unroll
        for (int j = 0; j < 4; ++j) {
            const int r = wn * 64 + j * 16 + (lane & 15);
            const int p = (kh * 4 + q4) ^ ((r >> 1) & 7);
            bf[j] = *(const f16x8*)&Bs[r * 64 + p * 8];
        }
        #pragma unroll
        for (int i = 0; i < 4; ++i)
            #pragma unroll
            for (int j = 0; j < 4; ++j)
                acc[i][j] = __builtin_amdgcn_mfma_f32_16x16x32_f16(af[i], bf[j], acc[i][j], 0, 0, 0);
    }

    const int quad = lane >> 4, cc = lane & 15;
    __syncthreads();

    #pragma unroll
    for (int i = 0; i < 4; ++i) {
        #pragma unroll
        for (int j = 0; j < 4; ++j) {
            const int col = wn * 64 + j * 16 + cc;
            #pragma unroll
            for (int r = 0; r < 4; ++r) {
                const int rl = wm * 64 + i * 16 + quad * 4 + r;
                Pt[col * 136 + rl] = (f16)(__expf(acc[i][j][r] - sqs[rl]) * MSCALE);
            }
        }
    }
    {
        const int vn = t >> 1;
        const int vhf = (t & 1) * 32;
        const f16* vbase = vh + (((size_t)bh << 10) + nt * 128 + vn) * 64 + vhf;
        #pragma unroll
        for (int k = 0; k < 4; ++k) {
            f16x8 vv = *(const f16x8*)&vbase[k * 8];
            #pragma unroll
            for (int e = 0; e < 8; ++e)
                vT[(vhf + k * 8 + e) * 136 + vn] = vv[e];
        }
    }
    __syncthreads();

    f32x4 acc2[4][2] = {};
    #pragma unroll
    for (int kt = 0; kt < 4; ++kt) {
        const int kb = kt * 32 + (lane >> 4) * 8;
        f16x8 af2[4], bf2[2];
        #pragma unroll
        for (int i = 0; i < 4; ++i)
            af2[i] = *(const f16x8*)&Pt[(wm * 64 + i * 16 + (lane & 15)) * 136 + kb];
        #pragma unroll
        for (int j = 0; j < 2; ++j)
            bf2[j] = *(const f16x8*)&vT[(wn * 32 + j * 16 + (lane & 15)) * 136 + kb];
        #pragma unroll
        for (int i = 0; i < 4; ++i)
            #pragma unroll
            for (int j = 0; j < 2; ++j)
                acc2[i][j] = __builtin_amdgcn_mfma_f32_16x16x32_f16(af2[i], bf2[j], acc2[i][j], 0, 0, 0);
    }

    float* kvo = kvf + (size_t)bh * 8192;
    #pragma unroll
    for (int i = 0; i < 4; ++i) {
        #pragma unroll
        for (int j = 0; j < 2; ++j) {
            const int d = wn * 32 + j * 16 + cc;
            #pragma unroll
            for (int r = 0; r < 4; ++r) {
                const int m = wm * 64 + i * 16 + quad * 4 + r;
                atomicAdd(&kvo[m * 64 + d], acc2[i][j][r]);
            }
        }
    }
    {
        const int sm = t >> 1, shf = (t & 1) * 64;
        float sp = 0.f;
        #pragma unroll
        for (int k = 0; k < 8; ++k) {
            f16x8 pv = *(const f16x8*)&Pt[sm * 136 + shf + k * 8];
            #pragma unroll
            for (int e = 0; e < 8; ++e) sp += (float)pv[e];
        }
        sp += __shfl_xor(sp, 1, 64);
        if ((t & 1) == 0) atomicAdd(&sf[(size_t)bh * 128 + sm], sp);
    }
}

// ---------------- fused feat(q) + denom + P@KV + divide (BK=64, 1 stage) ----------------
__global__ __launch_bounds__(256) void feat_apply(
        const f16* __restrict__ zq, const f16* __restrict__ Rt,
        const float* __restrict__ sqq, const float* __restrict__ kvf,
        const float* __restrict__ sf, f16* __restrict__ ohA)
{
    __shared__ __align__(16) char smem[52224];
    f16* As = (f16*)smem;
    f16* Bs = (f16*)(smem + 16384);
    f16* Pn = (f16*)smem;              // [128 n][136 m]
    f16* kvT = (f16*)(smem + 34816);   // [64 d][136 m]
    __shared__ float sqs[128], ssm[128], dns[128];

    const int t = threadIdx.x;
    const int wave = t >> 6, lane = t & 63;
    const int wm = wave >> 1, wn = wave & 1;
    const int nt = blockIdx.x, bh = blockIdx.y;
    const int b = bh / PH, h = bh % PH;

    const f16* A = zq + (((size_t)bh << 10) + nt * 128) * 64;
    const f16* Bm = Rt + (size_t)h * (PM * PD);

    if (t < 128) {
        sqs[t] = sqq[((size_t)bh << 10) + nt * 128 + t];
        ssm[t] = sf[(size_t)bh * 128 + t];
    }

    const int rowi = lane >> 3;
    const int cb = (lane & 7) ^ ((lane >> 4) & 3);
    const f16* ApE = A + (size_t)(wave * 32 + rowi) * 64 + cb * 8;
    const f16* ApO = A + (size_t)(wave * 32 + rowi) * 64 + (cb ^ 4) * 8;
    const f16* BpE = Bm + (size_t)(wave * 32 + rowi) * 64 + cb * 8;
    const f16* BpO = Bm + (size_t)(wave * 32 + rowi) * 64 + (cb ^ 4) * 8;
    f16* AsB = &As[wave * 32 * 64];
    f16* BsB = &Bs[wave * 32 * 64];
    GLL(ApE,            AsB);
    GLL(ApO + 8 * 64,   AsB + 8 * 64);
    GLL(ApE + 16 * 64,  AsB + 16 * 64);
    GLL(ApO + 24 * 64,  AsB + 24 * 64);
    GLL(BpE,            BsB);
    GLL(BpO + 8 * 64,   BsB + 8 * 64);
    GLL(BpE + 16 * 64,  BsB + 16 * 64);
    GLL(BpO + 24 * 64,  BsB + 24 * 64);
    __syncthreads();

    const int q4 = lane >> 4;
    f32x4 acc[4][4] = {};
    #pragma unroll
    for (int kh = 0; kh < 2; ++kh) {
        f16x8 af[4], bf[4];
        #pragma unroll
        for (int i = 0; i < 4; ++i) {
            const int r = wm * 64 + i * 16 + (lane & 15);
            const int p = (kh * 4 + q4) ^ ((r >> 1) & 7);
            af[i] = *(const f16x8*)&As[r * 64 + p * 8];
        }
        #pragma unroll
        for (int j = 0; j < 4; ++j) {
            const int r = wn * 64 + j * 16 + (lane & 15);
            const int p = (kh * 4 + q4) ^ ((r >> 1) & 7);
            bf[j] = *(const f16x8*)&Bs[r * 64 + p * 8];
        }
        #pragma unroll
        for (int i = 0; i < 4; ++i)
            #pragma unroll
            for (int j = 0; j < 4; ++j)
                acc[i][j] = __builtin_amdgcn_mfma_f32_16x16x32_f16(af[i], bf[j], acc[i][j], 0, 0, 0);
    }

    const int quad = lane >> 4, cc = lane & 15;
    __syncthreads();

    #pragma unroll
    for (int i = 0; i < 4; ++i) {
        #pragma unroll
        for (int j = 0; j < 4; ++j) {
            const int col = wn * 64 + j * 16 + cc;
            #pragma unroll
            for (int r = 0; r < 4; ++r) {
                const int rl = wm * 64 + i * 16 + quad * 4 + r;
                Pn[rl * 136 + col] = (f16)(__expf(acc[i][j][r] - sqs[rl]) * MSCALE);
            }
        }
    }
    {
        const int m = t >> 1;
        const int dh2 = (t & 1) * 32;
        const float* kvb = kvf + ((size_t)bh * 128 + m) * 64 + dh2;
        #pragma unroll
        for (int k = 0; k < 8; ++k) {
            float4 k4 = *(const float4*)&kvb[k * 4];
            kvT[(dh2 + k * 4 + 0) * 136 + m] = (f16)k4.x;
            kvT[(dh2 + k * 4 + 1) * 136 + m] = (f16)k4.y;
            kvT[(dh2 + k * 4 + 2) * 136 + m] = (f16)k4.z;
            kvT[(dh2 + k * 4 + 3) * 136 + m] = (f16)k4.w;
        }
    }
    __syncthreads();

    {
        const int n = t >> 1, mh = (t & 1) * 64;
        float p = 0.f;
        #pragma unroll
        for (int k = 0; k < 8; ++k) {
            f16x8 pv = *(const f16x8*)&Pn[n * 136 + mh + k * 8];
            #pragma unroll
            for (int e = 0; e < 8; ++e)
                p += (float)pv[e] * ssm[mh + k * 8 + e];
        }
        p += __shfl_xor(p, 1, 64);
        if ((t & 1) == 0) dns[n] = (p < 1e-12f) ? 1e-12f : p;
    }
    __syncthreads();

    f32x4 acc3[4][2] = {};
    #pragma unroll
    for (int kt = 0; kt < 4; ++kt) {
        const int kb = kt * 32 + (lane >> 4) * 8;
        f16x8 af3[4], bf3[2];
        #pragma unroll
        for (int i = 0; i < 4; ++i)
            af3[i] = *(const f16x8*)&Pn[(wm * 64 + i * 16 + (lane & 15)) * 136 + kb];
        #pragma unroll
        for (int j = 0; j < 2; ++j)
            bf3[j] = *(const f16x8*)&kvT[(wn * 32 + j * 16 + (lane & 15)) * 136 + kb];
        #pragma unroll
        for (int i = 0; i < 4; ++i)
            #pragma unroll
            for (int j = 0; j < 2; ++j)
                acc3[i][j] = __builtin_amdgcn_mfma_f32_16x16x32_f16(af3[i], bf3[j], acc3[i][j], 0, 0, 0);
    }

    f16* ob = ohA + ((size_t)(b * PN) + nt * 128) * PC + h * PD;
    #pragma unroll
    for (int i = 0; i < 4; ++i) {
        #pragma unroll
        for (int j = 0; j < 2; ++j) {
            const int d = wn * 32 + j * 16 + cc;
            #pragma unroll
            for (int r = 0; r < 4; ++r) {
                const int n = wm * 64 + i * 16 + quad * 4 + r;
                ob[(size_t)n * PC + d] = (f16)(acc3[i][j][r] / dns[n]);
            }
        }
    }
}

// ---------------- output projection GEMM (BK=64, BN=64), XCD-clustered grid ----------------
__global__ __launch_bounds__(256) void gemm_proj(
        const f16* __restrict__ A,    // [8192][768]
        const f16* __restrict__ Bm,   // [768][768]
        float* __restrict__ Cm, const float* __restrict__ bias)
{
    __shared__ f16 As[128 * 64];
    __shared__ f16 Bs[64 * 64];
    const int t = threadIdx.x;
    const int wave = t >> 6, lane = t & 63;
    const int wm = wave >> 1, wn = wave & 1;
    const int bi = blockIdx.x * 128, bj = blockIdx.y * 64;

    f32x4 acc[4][2] = {};

    const int rowi = lane >> 3;
    const int cb = (lane & 7) ^ ((lane >> 4) & 3);
    const f16* ApE = A + (size_t)(bi + wave * 32 + rowi) * PC + cb * 8;
    const f16* ApO = A + (size_t)(bi + wave * 32 + rowi) * PC + (cb ^ 4) * 8;
    const f16* BpE = Bm + (size_t)(bj + wave * 16 + rowi) * PC + cb * 8;
    const f16* BpO = Bm + (size_t)(bj + wave * 16 + rowi) * PC + (cb ^ 4) * 8;
    f16* AsB = &As[wave * 32 * 64];
    f16* BsB = &Bs[wave * 16 * 64];

    const int q4 = lane >> 4;
    for (int kt = 0; kt < 12; ++kt) {
        const int k0 = kt * 64;
        __syncthreads();
        GLL(ApE + k0,               AsB);
        GLL(ApO + k0 + (size_t) 8 * PC, AsB + 8 * 64);
        GLL(ApE + k0 + (size_t)16 * PC, AsB + 16 * 64);
        GLL(ApO + k0 + (size_t)24 * PC, AsB + 24 * 64);
        GLL(BpE + k0,               BsB);
        GLL(BpO + k0 + (size_t) 8 * PC, BsB + 8 * 64);
        __syncthreads();

        #pragma unroll
        for (int kh = 0; kh < 2; ++kh) {
            f16x8 af[4], bf[2];
            #pragma unroll
            for (int i = 0; i < 4; ++i) {
                const int r = wm * 64 + i * 16 + (lane & 15);
                const int p = (kh * 4 + q4) ^ ((r >> 1) & 7);
                af[i] = *(const f16x8*)&As[r * 64 + p * 8];
            }
            #pragma unroll
            for (int j = 0; j < 2; ++j) {
                const int r = wn * 32 + j * 16 + (lane & 15);
                const int p = (kh * 4 + q4) ^ ((r >> 1) & 7);
                bf[j] = *(const f16x8*)&Bs[r * 64 + p * 8];
            }
            #pragma unroll
            for (int i = 0; i < 4; ++i)
                #pragma unroll
                for (int j = 0; j < 2; ++j)
                    acc[i][j] = __builtin_amdgcn_mfma_f32_16x16x32_f16(af[i], bf[j], acc[i][j], 0, 0, 0);
        }
    }

    const int cr = (lane >> 4) * 4, cc = lane & 15;
    #pragma unroll
    for (int i = 0; i < 4; ++i) {
        const int row = bi + wm * 64 + i * 16 + cr;
        #pragma unroll
        for (int j = 0; j < 2; ++j) {
            const int col = bj + wn * 32 + j * 16 + cc;
            const float bv = bias[col];
            #pragma unroll
            for (int r = 0; r < 4; ++r)
                Cm[(size_t)(row + r) * PC + col] = acc[i][j][r] + bv;
        }
    }
}

extern "C" void kernel_launch(void* const* d_in, const int* in_sizes, int n_in,
                              void* d_out, int out_size, void* d_ws, size_t ws_size,
                              hipStream_t stream) {
    const float* x      = (const float*)d_in[0];
    const float* qkv_w  = (const float*)d_in[1];
    const float* proj_w = (const float*)d_in[2];
    const float* proj_b = (const float*)d_in[3];
    const float* rm     = (const float*)d_in[4];
    float* out = (float*)d_out;

    char* ws = (char*)d_ws;
    f16*   Ax   = (f16*)(ws);                     // [8192][768]      = 12,582,912
    f16*   Bqk  = (f16*)(ws + 12582912);          // [2304][768]      =  3,538,944
    f16*   Bp   = (f16*)(ws + 16121856);          // [768][768]       =  1,179,648
    f16*   Rt   = (f16*)(ws + 17301504);          // [12][128][64]    =    196,608
    f16*   zq   = (f16*)(ws + 17498112);          // [96][1024][64]   = 12,582,912
    f16*   zk   = (f16*)(ws + 30081024);          // [96][1024][64]   = 12,582,912
    f16*   vh   = (f16*)(ws + 42663936);          // [96][1024][64]   = 12,582,912
    float* sqq  = (float*)(ws + 55246848);        // [96][1024] f32   =    393,216
    float* sqk  = (float*)(ws + 55640064);        // [96][1024] f32   =    393,216
    float* kvf  = (float*)(ws + 56033280);        // [96][128][64] f32=  3,145,728
    float* sf   = (float*)(ws + 59179008);        // [96][128] f32    =     49,152
    f16*   ohA  = (f16*)(ws + 59228160);          // [8192][768]      = 12,582,912

    // 1) conversions + zero-init kvf/sf (accumulated by atomics in feat_kv)
    conv_all<<<12316, 192, 0, stream>>>(x, qkv_w, proj_w, rm, Ax, Bqk, Bp, Rt, kvf, sf);

    // 2) fused qkv projection -> z_q, z_k (f16+sqnorm), v (f16)
    gemm_qkv<<<dim3(64, 18), 256, 0, stream>>>(Ax, Bqk, zq, zk, vh, sqq, sqk);

    // 3) fused feat(k) + kf^T@V + colsum, atomic accumulate into kvf/sf
    feat_kv<<<dim3(8, 96), 256, 0, stream>>>(zk, Rt, sqk, vh, kvf, sf);

    // 4) fused feat(q) + denom + P@KV -> ohA
    feat_apply<<<dim3(8, 96), 256, 0, stream>>>(zq, Rt, sqq, kvf, sf, ohA);

    // 5) out = oh @ proj_w^T + proj_b
    gemm_proj<<<dim3(64, 12), 256, 0, stream>>>(ohA, Bp, out, proj_b);
}